// Round 1
// baseline (942.490 us; speedup 1.0000x reference)
//
#include <hip/hip_runtime.h>
#include <math.h>

#define NN   100000
#define NE   1600000
#define INC  32
#define HID  64
#define OUTC 40

// ---------------------------------------------------------------------------
// Edge pass 1: scatter (1-p)*x[src] and p*x[src] into A[dst][0:32]/A[dst][32:64]
// 32 lanes per edge (one per input feature). Also counts edges per dst.
// ---------------------------------------------------------------------------
__global__ __launch_bounds__(256) void k_edge1(
    const float* __restrict__ x, const int* __restrict__ src,
    const int* __restrict__ dst, const float* __restrict__ pseudo,
    float* __restrict__ A, float* __restrict__ cnt)
{
    int e = blockIdx.x * 8 + (threadIdx.x >> 5);
    int lane = threadIdx.x & 31;
    if (e >= NE) return;
    int s = src[e], d = dst[e];
    float p = pseudo[e];
    float xv = x[(size_t)s * INC + lane];
    float* Ad = A + (size_t)d * 64;
    atomicAdd(Ad + lane, (1.0f - p) * xv);
    atomicAdd(Ad + 32 + lane, p * xv);
    if (lane == 0) atomicAdd(cnt + d, 1.0f);
}

// ---------------------------------------------------------------------------
// Node pass 1: agg = (A0@W1[0] + A1@W1[1]) / max(cnt,1) + x@root1 + b1 ; ELU
// then precompute hw2[n][k][o] = h[n]@W2[k]   (layout [n][80], k-major)
// One thread per node; weights staged in LDS.
// ---------------------------------------------------------------------------
__global__ __launch_bounds__(256) void k_node1(
    const float* __restrict__ A, const float* __restrict__ x,
    const float* __restrict__ cnt,
    const float* __restrict__ W1, const float* __restrict__ root1,
    const float* __restrict__ b1, const float* __restrict__ W2,
    float* __restrict__ h, float* __restrict__ hw2)
{
    __shared__ float sW0[INC * HID];
    __shared__ float sW1[INC * HID];
    __shared__ float sR [INC * HID];
    __shared__ float sW2[2 * HID * OUTC];
    __shared__ float sb1[HID];

    for (int i = threadIdx.x; i < INC * HID; i += 256) {
        sW0[i] = W1[i];
        sW1[i] = W1[INC * HID + i];
        sR [i] = root1[i];
    }
    for (int i = threadIdx.x; i < 2 * HID * OUTC; i += 256) sW2[i] = W2[i];
    if (threadIdx.x < HID) sb1[threadIdx.x] = b1[threadIdx.x];
    __syncthreads();

    int n = blockIdx.x * 256 + threadIdx.x;
    if (n >= NN) return;

    float acc[HID];
#pragma unroll
    for (int o = 0; o < HID; o++) acc[o] = 0.0f;

    const float* Ar = A + (size_t)n * 64;
    for (int f = 0; f < INC; f++) {
        float a0 = Ar[f], a1 = Ar[32 + f];
        const float* w0 = sW0 + f * HID;
        const float* w1 = sW1 + f * HID;
#pragma unroll
        for (int o = 0; o < HID; o++)
            acc[o] = fmaf(a0, w0[o], fmaf(a1, w1[o], acc[o]));
    }

    float inv = 1.0f / fmaxf(cnt[n], 1.0f);
#pragma unroll
    for (int o = 0; o < HID; o++) acc[o] *= inv;

    const float* xr = x + (size_t)n * INC;
    for (int f = 0; f < INC; f++) {
        float xv = xr[f];
        const float* wr = sR + f * HID;
#pragma unroll
        for (int o = 0; o < HID; o++) acc[o] = fmaf(xv, wr[o], acc[o]);
    }

    float* hr = h + (size_t)n * HID;
#pragma unroll
    for (int o = 0; o < HID; o++) {
        float v = acc[o] + sb1[o];
        v = (v > 0.0f) ? v : (expf(v) - 1.0f);
        hr[o] = v;
    }

    // hw2[n][k*40+o] = sum_f h[f] * W2[k][f][o]  (h re-read via L1, f-loop rolled)
    float* hwr = hw2 + (size_t)n * 80;
    for (int k = 0; k < 2; k++) {
        float a2[OUTC];
#pragma unroll
        for (int o = 0; o < OUTC; o++) a2[o] = 0.0f;
        const float* wbase = sW2 + k * HID * OUTC;
        for (int f = 0; f < HID; f++) {
            float hv = hr[f];
            const float* w = wbase + f * OUTC;
#pragma unroll
            for (int o = 0; o < OUTC; o++) a2[o] = fmaf(hv, w[o], a2[o]);
        }
#pragma unroll
        for (int o = 0; o < OUTC; o++) hwr[k * OUTC + o] = a2[o];
    }
}

// ---------------------------------------------------------------------------
// Edge pass 2: gather hw2[src], interpolate by p, scatter-add 40 floats to agg[dst]
// 8 lanes per edge, 5 features each.
// ---------------------------------------------------------------------------
__global__ __launch_bounds__(256) void k_edge2(
    const float* __restrict__ hw2, const int* __restrict__ src,
    const int* __restrict__ dst, const float* __restrict__ pseudo,
    float* __restrict__ agg)
{
    int e = blockIdx.x * 32 + (threadIdx.x >> 3);
    int lane = threadIdx.x & 7;
    if (e >= NE) return;
    int s = src[e], d = dst[e];
    float p = pseudo[e];
    const float* g = hw2 + (size_t)s * 80;
    float* ad = agg + (size_t)d * 40;
#pragma unroll
    for (int j = 0; j < 5; j++) {
        int o = lane + 8 * j;
        float g0 = g[o], g1 = g[40 + o];
        atomicAdd(ad + o, fmaf(p, g1 - g0, g0));
    }
}

// ---------------------------------------------------------------------------
// Final: out = log_softmax( agg/max(cnt,1) + h@root2 + b2 )
// ---------------------------------------------------------------------------
__global__ __launch_bounds__(256) void k_final(
    const float* __restrict__ h, const float* __restrict__ agg,
    const float* __restrict__ cnt, const float* __restrict__ root2,
    const float* __restrict__ b2, float* __restrict__ out)
{
    __shared__ float sR[HID * OUTC];
    __shared__ float sb[OUTC];
    for (int i = threadIdx.x; i < HID * OUTC; i += 256) sR[i] = root2[i];
    if (threadIdx.x < OUTC) sb[threadIdx.x] = b2[threadIdx.x];
    __syncthreads();

    int n = blockIdx.x * 256 + threadIdx.x;
    if (n >= NN) return;

    float inv = 1.0f / fmaxf(cnt[n], 1.0f);
    float acc[OUTC];
    const float* ar = agg + (size_t)n * OUTC;
#pragma unroll
    for (int o = 0; o < OUTC; o++) acc[o] = fmaf(ar[o], inv, sb[o]);

    const float* hr = h + (size_t)n * HID;
    for (int f = 0; f < HID; f++) {
        float hv = hr[f];
        const float* w = sR + f * OUTC;
#pragma unroll
        for (int o = 0; o < OUTC; o++) acc[o] = fmaf(hv, w[o], acc[o]);
    }

    float m = -1e30f;
#pragma unroll
    for (int o = 0; o < OUTC; o++) m = fmaxf(m, acc[o]);
    float ssum = 0.0f;
#pragma unroll
    for (int o = 0; o < OUTC; o++) ssum += expf(acc[o] - m);
    float lse = m + logf(ssum);

    float* outr = out + (size_t)n * OUTC;
#pragma unroll
    for (int o = 0; o < OUTC; o++) outr[o] = acc[o] - lse;
}

// ---------------------------------------------------------------------------
extern "C" void kernel_launch(void* const* d_in, const int* in_sizes, int n_in,
                              void* d_out, int out_size, void* d_ws, size_t ws_size,
                              hipStream_t stream)
{
    const float* x     = (const float*)d_in[0];
    const int*   ei    = (const int*)  d_in[1];
    const float* ea    = (const float*)d_in[2];
    const float* W1    = (const float*)d_in[3];
    const float* root1 = (const float*)d_in[4];
    const float* b1    = (const float*)d_in[5];
    const float* W2    = (const float*)d_in[6];
    const float* root2 = (const float*)d_in[7];
    const float* b2    = (const float*)d_in[8];
    float* out = (float*)d_out;

    const int* src = ei;
    const int* dst = ei + NE;

    // workspace layout (floats):
    //  A    : NN*64  (layer-1 input-space accumulators; reused as agg2 NN*40)
    //  h    : NN*64
    //  hw2  : NN*80
    //  cnt  : NN
    float* ws  = (float*)d_ws;
    float* A   = ws;
    float* h   = A   + (size_t)NN * 64;
    float* hw2 = h   + (size_t)NN * 64;
    float* cnt = hw2 + (size_t)NN * 80;

    hipMemsetAsync(A,   0, (size_t)NN * 64 * sizeof(float), stream);
    hipMemsetAsync(cnt, 0, (size_t)NN * sizeof(float), stream);

    k_edge1<<<NE / 8, 256, 0, stream>>>(x, src, dst, ea, A, cnt);
    k_node1<<<(NN + 255) / 256, 256, 0, stream>>>(A, x, cnt, W1, root1, b1, W2, h, hw2);

    // reuse A as agg2 (N x 40)
    hipMemsetAsync(A, 0, (size_t)NN * 40 * sizeof(float), stream);
    k_edge2<<<NE / 32, 256, 0, stream>>>(hw2, src, dst, ea, A);
    k_final<<<(NN + 255) / 256, 256, 0, stream>>>(h, A, cnt, root2, b2, out);
}

// Round 3
// 796.561 us; speedup vs baseline: 1.1832x; 1.1832x over previous
//
#include <hip/hip_runtime.h>
#include <math.h>

#define NN   100000
#define NE   1600000
#define INC  32
#define HID  64
#define OUTC 40

// ---------------------------------------------------------------------------
// CSR build step 1: histogram of dst (also serves as per-node edge count)
// ---------------------------------------------------------------------------
__global__ __launch_bounds__(256) void k_hist(const int* __restrict__ dst,
                                              int* __restrict__ cnt)
{
    int e = blockIdx.x * 256 + threadIdx.x;   // NE divisible by 256
    atomicAdd(&cnt[dst[e]], 1);
}

// CSR build step 2a: per-block (512 elems) sums of cnt
__global__ __launch_bounds__(512) void k_scan1(const int* __restrict__ cnt,
                                               int* __restrict__ bsum)
{
    __shared__ int red[512];
    int i = blockIdx.x * 512 + threadIdx.x;
    red[threadIdx.x] = (i < NN) ? cnt[i] : 0;
    __syncthreads();
    for (int off = 256; off > 0; off >>= 1) {
        if (threadIdx.x < off) red[threadIdx.x] += red[threadIdx.x + off];
        __syncthreads();
    }
    if (threadIdx.x == 0) bsum[blockIdx.x] = red[0];
}

// CSR build step 2b: exclusive scan of the block sums (tiny, serial)
__global__ void k_scan2(int* bsum, int nb)
{
    if (threadIdx.x == 0) {
        int run = 0;
        for (int i = 0; i < nb; i++) { int v = bsum[i]; bsum[i] = run; run += v; }
    }
}

// CSR build step 2c: in-block exclusive scan + block offset -> offs, cursor
__global__ __launch_bounds__(512) void k_scan3(const int* __restrict__ cnt,
                                               const int* __restrict__ bsum,
                                               int* __restrict__ offs,
                                               int* __restrict__ cursor)
{
    __shared__ int tmp[512];
    int t = threadIdx.x;
    int i = blockIdx.x * 512 + t;
    int v = (i < NN) ? cnt[i] : 0;
    tmp[t] = v;
    __syncthreads();
    for (int off = 1; off < 512; off <<= 1) {
        int add = (t >= off) ? tmp[t - off] : 0;
        __syncthreads();
        tmp[t] += add;
        __syncthreads();
    }
    int excl = tmp[t] - v;
    if (i < NN) {
        int o = bsum[blockIdx.x] + excl;
        offs[i] = o;
        cursor[i] = o;
    }
}

// CSR build step 3: scatter edge payloads {src, p} into dst-sorted order
__global__ __launch_bounds__(256) void k_scatter(const int* __restrict__ src,
                                                 const int* __restrict__ dst,
                                                 const float* __restrict__ pseudo,
                                                 int* __restrict__ cursor,
                                                 int2* __restrict__ pay)
{
    int e = blockIdx.x * 256 + threadIdx.x;
    int d = dst[e];
    int pos = atomicAdd(&cursor[d], 1);
    pay[pos] = make_int2(src[e], __float_as_int(pseudo[e]));
}

// ---------------------------------------------------------------------------
// Layer 1 fused: wave per node. Lanes 0-31 accumulate sum((1-p)*x[s]),
// lanes 32-63 accumulate sum(p*x[s]); LDS matvec with W1[0]/W1[1];
// + x@root1 + b1; ELU.
// ---------------------------------------------------------------------------
__global__ __launch_bounds__(256) void k_agg1h(
    const float* __restrict__ x, const int2* __restrict__ pay,
    const int* __restrict__ offs, const int* __restrict__ cnt,
    const float* __restrict__ W1, const float* __restrict__ root1,
    const float* __restrict__ b1, float* __restrict__ h)
{
    __shared__ float sW0[INC * HID], sW1[INC * HID], sR[INC * HID], sb1[HID];
    __shared__ float scr[4][HID];
    int t = threadIdx.x;
    for (int i = t; i < INC * HID; i += 256) {
        sW0[i] = W1[i];
        sW1[i] = W1[INC * HID + i];
        sR [i] = root1[i];
    }
    if (t < HID) sb1[t] = b1[t];
    __syncthreads();

    int w = t >> 6, lane = t & 63;
    int f = lane & 31, half = lane >> 5;

    for (int n0 = blockIdx.x * 4; n0 < NN; n0 += gridDim.x * 4) {
        int n = n0 + w;
        int e0 = offs[n], c = cnt[n];

        float acc = 0.0f;
        for (int e = e0; e < e0 + c; ++e) {
            int2 pr = pay[e];
            float p = __int_as_float(pr.y);
            float xv = x[(size_t)pr.x * INC + f];
            acc = fmaf(half ? p : (1.0f - p), xv, acc);   // W1[0] operand: sum (1-p)x
        }
        scr[w][lane] = acc;           // wave-private LDS; lockstep
        asm volatile("" ::: "memory");

        float o_acc = 0.0f;
        int o = lane;
#pragma unroll
        for (int ff = 0; ff < INC; ++ff) {
            float sX = scr[w][ff], sP = scr[w][INC + ff];
            o_acc = fmaf(sX, sW0[ff * HID + o], fmaf(sP, sW1[ff * HID + o], o_acc));
        }
        o_acc *= 1.0f / fmaxf((float)c, 1.0f);

        asm volatile("" ::: "memory");
        if (lane < INC) scr[w][lane] = x[(size_t)n * INC + lane];
        asm volatile("" ::: "memory");
#pragma unroll
        for (int ff = 0; ff < INC; ++ff)
            o_acc = fmaf(scr[w][ff], sR[ff * HID + o], o_acc);

        float v = o_acc + sb1[o];
        v = (v > 0.0f) ? v : (expf(v) - 1.0f);
        h[(size_t)n * HID + o] = v;
    }
}

// ---------------------------------------------------------------------------
// Precompute hw2[n][o][k] = (h[n] @ W2[k])[o], interleaved so layer-2 gathers
// are one float2 per lane.
// ---------------------------------------------------------------------------
__global__ __launch_bounds__(256) void k_hw2(
    const float* __restrict__ h, const float* __restrict__ W2,
    float* __restrict__ hw2)
{
    __shared__ float sW2[2 * HID * OUTC];
    int t = threadIdx.x;
    for (int i = t; i < 2 * HID * OUTC; i += 256) sW2[i] = W2[i];
    __syncthreads();

    int n = blockIdx.x * 256 + t;
    if (n >= NN) return;

    const float* hr = h + (size_t)n * HID;
    float a0[OUTC], a1[OUTC];
#pragma unroll
    for (int o = 0; o < OUTC; o++) { a0[o] = 0.0f; a1[o] = 0.0f; }
    for (int f = 0; f < HID; f++) {
        float hv = hr[f];
        const float* w0 = sW2 + f * OUTC;
        const float* w1 = sW2 + HID * OUTC + f * OUTC;
#pragma unroll
        for (int o = 0; o < OUTC; o++) {
            a0[o] = fmaf(hv, w0[o], a0[o]);
            a1[o] = fmaf(hv, w1[o], a1[o]);
        }
    }
    float4* hp = (float4*)(hw2 + (size_t)n * (2 * OUTC));
#pragma unroll
    for (int o = 0; o < OUTC; o += 2)
        hp[o >> 1] = make_float4(a0[o], a1[o], a0[o + 1], a1[o + 1]);
}

// ---------------------------------------------------------------------------
// Layer 2 fused: wave per node. Lanes 0-39 gather float2 (g0,g1) per edge,
// interpolate, accumulate; then /cnt + h@root2 + b2 + log_softmax (shuffles).
// ---------------------------------------------------------------------------
__global__ __launch_bounds__(256) void k_agg2f(
    const float* __restrict__ h, const float* __restrict__ hw2,
    const int2* __restrict__ pay, const int* __restrict__ offs,
    const int* __restrict__ cnt, const float* __restrict__ root2,
    const float* __restrict__ b2, float* __restrict__ out)
{
    __shared__ float sR[HID * OUTC], sb[OUTC];
    __shared__ float scr[4][HID];
    int t = threadIdx.x;
    for (int i = t; i < HID * OUTC; i += 256) sR[i] = root2[i];
    if (t < OUTC) sb[t] = b2[t];
    __syncthreads();

    int w = t >> 6, lane = t & 63;
    int o = (lane < OUTC) ? lane : 0;

    for (int n0 = blockIdx.x * 4; n0 < NN; n0 += gridDim.x * 4) {
        int n = n0 + w;
        int e0 = offs[n], c = cnt[n];

        float acc = 0.0f;
        for (int e = e0; e < e0 + c; ++e) {
            int2 pr = pay[e];
            float p = __int_as_float(pr.y);
            if (lane < OUTC) {
                float2 g = *(const float2*)(hw2 + (size_t)pr.x * (2 * OUTC) + lane * 2);
                acc += fmaf(p, g.y - g.x, g.x);
            }
        }
        acc *= 1.0f / fmaxf((float)c, 1.0f);

        asm volatile("" ::: "memory");
        scr[w][lane] = h[(size_t)n * HID + lane];   // wave-private, lockstep
        asm volatile("" ::: "memory");
        float r = (lane < OUTC) ? (acc + sb[lane]) : 0.0f;
#pragma unroll
        for (int ff = 0; ff < HID; ++ff)
            r = fmaf(scr[w][ff], sR[ff * OUTC + o], r);

        float m = (lane < OUTC) ? r : -1e30f;
#pragma unroll
        for (int off = 32; off > 0; off >>= 1) m = fmaxf(m, __shfl_xor(m, off));
        float ex = (lane < OUTC) ? expf(r - m) : 0.0f;
#pragma unroll
        for (int off = 32; off > 0; off >>= 1) ex += __shfl_xor(ex, off);
        float lse = m + logf(ex);

        if (lane < OUTC) out[(size_t)n * OUTC + lane] = r - lse;
    }
}

// ---------------------------------------------------------------------------
extern "C" void kernel_launch(void* const* d_in, const int* in_sizes, int n_in,
                              void* d_out, int out_size, void* d_ws, size_t ws_size,
                              hipStream_t stream)
{
    const float* x     = (const float*)d_in[0];
    const int*   ei    = (const int*)  d_in[1];
    const float* ea    = (const float*)d_in[2];
    const float* W1    = (const float*)d_in[3];
    const float* root1 = (const float*)d_in[4];
    const float* b1    = (const float*)d_in[5];
    const float* W2    = (const float*)d_in[6];
    const float* root2 = (const float*)d_in[7];
    const float* b2    = (const float*)d_in[8];
    float* out = (float*)d_out;

    const int* src = ei;
    const int* dst = ei + NE;

    // workspace layout
    char* wsp = (char*)d_ws;
    int*  cnt    = (int*)wsp;  wsp += sizeof(int) * NN;       // 400 KB
    int*  offs   = (int*)wsp;  wsp += sizeof(int) * NN;       // 400 KB
    int*  cursor = (int*)wsp;  wsp += sizeof(int) * NN;       // 400 KB
    int*  bsum   = (int*)wsp;  wsp += sizeof(int) * 256;      // 1 KB
    int2* pay    = (int2*)wsp; wsp += sizeof(int2) * NE;      // 12.8 MB
    float* h     = (float*)wsp; wsp += sizeof(float) * (size_t)NN * HID;      // 25.6 MB
    float* hw2   = (float*)wsp; wsp += sizeof(float) * (size_t)NN * 2 * OUTC; // 32 MB

    hipMemsetAsync(cnt, 0, sizeof(int) * NN, stream);

    int nb = (NN + 511) / 512;   // 196
    k_hist   <<<NE / 256, 256, 0, stream>>>(dst, cnt);
    k_scan1  <<<nb, 512, 0, stream>>>(cnt, bsum);
    k_scan2  <<<1, 64, 0, stream>>>(bsum, nb);
    k_scan3  <<<nb, 512, 0, stream>>>(cnt, bsum, offs, cursor);
    k_scatter<<<NE / 256, 256, 0, stream>>>(src, dst, ea, cursor, pay);

    k_agg1h  <<<2048, 256, 0, stream>>>(x, pay, offs, cnt, W1, root1, b1, h);
    k_hw2    <<<(NN + 255) / 256, 256, 0, stream>>>(h, W2, hw2);
    k_agg2f  <<<2048, 256, 0, stream>>>(h, hw2, pay, offs, cnt, root2, b2, out);
}

// Round 4
// 467.579 us; speedup vs baseline: 2.0157x; 1.7036x over previous
//
#include <hip/hip_runtime.h>
#include <math.h>

#define NN   100000
#define NE   1600000
#define INC  32
#define HID  64
#define OUTC 40

// bf16 helpers (round-to-nearest-even)
__device__ inline unsigned f2bf(float f) {
    unsigned u = __float_as_uint(f);
    return (u + 0x7fffu + ((u >> 16) & 1u)) >> 16;
}
__device__ inline unsigned packbf(float a, float b) {
    return f2bf(a) | (f2bf(b) << 16);
}

// ---------------------------------------------------------------------------
// CSR build
// ---------------------------------------------------------------------------
__global__ __launch_bounds__(256) void k_hist(const int* __restrict__ dst,
                                              int* __restrict__ cnt)
{
    int e = blockIdx.x * 256 + threadIdx.x;
    atomicAdd(&cnt[dst[e]], 1);
}

__global__ __launch_bounds__(512) void k_scan1(const int* __restrict__ cnt,
                                               int* __restrict__ bsum)
{
    __shared__ int red[512];
    int i = blockIdx.x * 512 + threadIdx.x;
    red[threadIdx.x] = (i < NN) ? cnt[i] : 0;
    __syncthreads();
    for (int off = 256; off > 0; off >>= 1) {
        if (threadIdx.x < off) red[threadIdx.x] += red[threadIdx.x + off];
        __syncthreads();
    }
    if (threadIdx.x == 0) bsum[blockIdx.x] = red[0];
}

__global__ void k_scan2(int* bsum, int nb)
{
    if (threadIdx.x == 0) {
        int run = 0;
        for (int i = 0; i < nb; i++) { int v = bsum[i]; bsum[i] = run; run += v; }
    }
}

__global__ __launch_bounds__(512) void k_scan3(const int* __restrict__ cnt,
                                               const int* __restrict__ bsum,
                                               int* __restrict__ offs,
                                               int* __restrict__ cursor)
{
    __shared__ int tmp[512];
    int t = threadIdx.x;
    int i = blockIdx.x * 512 + t;
    int v = (i < NN) ? cnt[i] : 0;
    tmp[t] = v;
    __syncthreads();
    for (int off = 1; off < 512; off <<= 1) {
        int add = (t >= off) ? tmp[t - off] : 0;
        __syncthreads();
        tmp[t] += add;
        __syncthreads();
    }
    int excl = tmp[t] - v;
    if (i < NN) {
        int o = bsum[blockIdx.x] + excl;
        offs[i] = o;
        cursor[i] = o;
    }
}

__global__ __launch_bounds__(256) void k_scatter(const int* __restrict__ src,
                                                 const int* __restrict__ dst,
                                                 const float* __restrict__ pseudo,
                                                 int* __restrict__ cursor,
                                                 int2* __restrict__ pay)
{
    int e = blockIdx.x * 256 + threadIdx.x;
    int d = dst[e];
    int pos = atomicAdd(&cursor[d], 1);
    pay[pos] = make_int2(src[e], __float_as_int(pseudo[e]));
}

// ---------------------------------------------------------------------------
// Layer 1: wave per node, 8 edges gathered per vmem instruction.
// lane = slot*8 + quad; slot = edge slot (0..7), quad = feature quad (0..7).
// a0 accumulates sum((1-p)x), a1 accumulates sum(p*x) for features quad*4..+3.
// ---------------------------------------------------------------------------
__global__ __launch_bounds__(256) void k_agg1h(
    const float* __restrict__ x, const int2* __restrict__ pay,
    const int* __restrict__ offs, const int* __restrict__ cnt,
    const float* __restrict__ W1, const float* __restrict__ root1,
    const float* __restrict__ b1, float* __restrict__ h)
{
    __shared__ float sW0[INC * HID], sW1[INC * HID], sR[INC * HID], sb1[HID];
    __shared__ float scr[4][HID];
    int t = threadIdx.x;
    for (int i = t; i < INC * HID; i += 256) {
        sW0[i] = W1[i];
        sW1[i] = W1[INC * HID + i];
        sR [i] = root1[i];
    }
    if (t < HID) sb1[t] = b1[t];
    __syncthreads();

    int w = t >> 6, lane = t & 63;
    int slot = lane >> 3, quad = lane & 7;

    for (int n0 = blockIdx.x * 4; n0 < NN; n0 += gridDim.x * 4) {
        int n = n0 + w;
        int e0 = offs[n], c = cnt[n];

        float4 a0 = make_float4(0.f, 0.f, 0.f, 0.f);
        float4 a1 = make_float4(0.f, 0.f, 0.f, 0.f);

        for (int base = 0; base < c; base += 64) {
            int bc = min(c - base, 64);
            int li = (lane < bc) ? lane : (bc - 1);
            int2 pl = pay[e0 + base + li];
            for (int g = 0; g < bc; g += 8) {
                int je = g + slot;                       // <= 63
                int   sj = __shfl(pl.x, je);
                float pj = __int_as_float(__shfl(pl.y, je));
                bool valid = je < bc;
                float w1v = valid ? pj : 0.0f;
                float w0v = valid ? (1.0f - pj) : 0.0f;
                float4 xv = *((const float4*)(x + (size_t)sj * INC) + quad);
                a0.x = fmaf(w0v, xv.x, a0.x); a0.y = fmaf(w0v, xv.y, a0.y);
                a0.z = fmaf(w0v, xv.z, a0.z); a0.w = fmaf(w0v, xv.w, a0.w);
                a1.x = fmaf(w1v, xv.x, a1.x); a1.y = fmaf(w1v, xv.y, a1.y);
                a1.z = fmaf(w1v, xv.z, a1.z); a1.w = fmaf(w1v, xv.w, a1.w);
            }
        }

        // reduce 8 slots (lane bits 3..5)
#pragma unroll
        for (int mask = 8; mask <= 32; mask <<= 1) {
            a0.x += __shfl_xor(a0.x, mask); a0.y += __shfl_xor(a0.y, mask);
            a0.z += __shfl_xor(a0.z, mask); a0.w += __shfl_xor(a0.w, mask);
            a1.x += __shfl_xor(a1.x, mask); a1.y += __shfl_xor(a1.y, mask);
            a1.z += __shfl_xor(a1.z, mask); a1.w += __shfl_xor(a1.w, mask);
        }
        asm volatile("" ::: "memory");
        if (slot == 0) {
            scr[w][quad * 4 + 0] = a0.x; scr[w][quad * 4 + 1] = a0.y;
            scr[w][quad * 4 + 2] = a0.z; scr[w][quad * 4 + 3] = a0.w;
            scr[w][32 + quad * 4 + 0] = a1.x; scr[w][32 + quad * 4 + 1] = a1.y;
            scr[w][32 + quad * 4 + 2] = a1.z; scr[w][32 + quad * 4 + 3] = a1.w;
        }
        asm volatile("" ::: "memory");

        float o_acc = 0.0f;
        int o = lane;
#pragma unroll
        for (int ff = 0; ff < INC; ++ff) {
            float sX = scr[w][ff], sP = scr[w][INC + ff];
            o_acc = fmaf(sX, sW0[ff * HID + o], fmaf(sP, sW1[ff * HID + o], o_acc));
        }
        o_acc *= 1.0f / fmaxf((float)c, 1.0f);

        asm volatile("" ::: "memory");
        if (lane < INC) scr[w][lane] = x[(size_t)n * INC + lane];
        asm volatile("" ::: "memory");
#pragma unroll
        for (int ff = 0; ff < INC; ++ff)
            o_acc = fmaf(scr[w][ff], sR[ff * HID + o], o_acc);

        float v = o_acc + sb1[o];
        v = (v > 0.0f) ? v : (expf(v) - 1.0f);
        h[(size_t)n * HID + o] = v;
    }
}

// ---------------------------------------------------------------------------
// Precompute:  hw2b[n] = bf16 interleaved (g0[o],g1[o]) pairs, g_k = h[n]@W2[k]
//              rt[n]   = h[n]@root2 + b2   (fp32)
// ---------------------------------------------------------------------------
__global__ __launch_bounds__(256) void k_hw2(
    const float* __restrict__ h, const float* __restrict__ W2,
    const float* __restrict__ root2, const float* __restrict__ b2,
    unsigned* __restrict__ hw2b, float* __restrict__ rt)
{
    __shared__ float sW2[2 * HID * OUTC];   // 20 KB
    __shared__ float sR2[HID * OUTC];       // 10 KB
    __shared__ float sb2[OUTC];
    int t = threadIdx.x;
    for (int i = t; i < 2 * HID * OUTC; i += 256) sW2[i] = W2[i];
    for (int i = t; i < HID * OUTC; i += 256) sR2[i] = root2[i];
    if (t < OUTC) sb2[t] = b2[t];
    __syncthreads();

    int n = blockIdx.x * 256 + t;
    if (n >= NN) return;

    const float4* hp = (const float4*)(h + (size_t)n * HID);

    // pass 1: g0/g1
    float a0[OUTC], a1[OUTC];
#pragma unroll
    for (int o = 0; o < OUTC; o++) { a0[o] = 0.0f; a1[o] = 0.0f; }
    for (int f4 = 0; f4 < HID / 4; f4++) {
        float4 hv = hp[f4];
        float hj[4] = {hv.x, hv.y, hv.z, hv.w};
#pragma unroll
        for (int j = 0; j < 4; j++) {
            int f = f4 * 4 + j;
            const float* w0 = sW2 + f * OUTC;
            const float* w1 = sW2 + HID * OUTC + f * OUTC;
#pragma unroll
            for (int o = 0; o < OUTC; o++) {
                a0[o] = fmaf(hj[j], w0[o], a0[o]);
                a1[o] = fmaf(hj[j], w1[o], a1[o]);
            }
        }
    }
    uint2* gp = (uint2*)(hw2b + (size_t)n * 40);
#pragma unroll
    for (int o = 0; o < OUTC; o += 2)
        gp[o >> 1] = make_uint2(packbf(a0[o], a1[o]), packbf(a0[o + 1], a1[o + 1]));

    // pass 2: rt = h@root2 + b2
    float ar[OUTC];
#pragma unroll
    for (int o = 0; o < OUTC; o++) ar[o] = sb2[o];
    for (int f4 = 0; f4 < HID / 4; f4++) {
        float4 hv = hp[f4];
        float hj[4] = {hv.x, hv.y, hv.z, hv.w};
#pragma unroll
        for (int j = 0; j < 4; j++) {
            const float* wr = sR2 + (f4 * 4 + j) * OUTC;
#pragma unroll
            for (int o = 0; o < OUTC; o++) ar[o] = fmaf(hj[j], wr[o], ar[o]);
        }
    }
    float4* rp = (float4*)(rt + (size_t)n * OUTC);
#pragma unroll
    for (int o = 0; o < OUTC; o += 4)
        rp[o >> 2] = make_float4(ar[o], ar[o + 1], ar[o + 2], ar[o + 3]);
}

// ---------------------------------------------------------------------------
// Layer 2: wave per node, 3 edges per vmem instruction (20 lanes x uint2 each
// = 4 bf16 = outputs 2m,2m+1 both knots). Reduce 3 slots, + rt, log_softmax.
// ---------------------------------------------------------------------------
__global__ __launch_bounds__(256) void k_agg2f(
    const unsigned* __restrict__ hw2b, const float* __restrict__ rt,
    const int2* __restrict__ pay, const int* __restrict__ offs,
    const int* __restrict__ cnt, float* __restrict__ out)
{
    __shared__ float scr[4][HID];
    int t = threadIdx.x;
    int w = t >> 6, lane = t & 63;
    int slot = lane / 20;            // 0..2 active, 3 = idle lanes 60-63
    int m = lane - slot * 20;        // 0..19 -> outputs 2m, 2m+1

    for (int n0 = blockIdx.x * 4; n0 < NN; n0 += gridDim.x * 4) {
        int n = n0 + w;
        int e0 = offs[n], c = cnt[n];

        float acc0 = 0.0f, acc1 = 0.0f;
        for (int base = 0; base < c; base += 64) {
            int bc = min(c - base, 64);
            int li = (lane < bc) ? lane : (bc - 1);
            int2 pl = pay[e0 + base + li];
            for (int g = 0; g < bc; g += 3) {
                int je = g + slot;
                int js = je & 63;
                int   sj = __shfl(pl.x, js);
                float pj = __int_as_float(__shfl(pl.y, js));
                bool valid = (slot < 3) && (je < bc);
                uint2 gv = *((const uint2*)(hw2b + (size_t)sj * 40) + m);
                float g00 = __uint_as_float(gv.x << 16);
                float g10 = __uint_as_float(gv.x & 0xffff0000u);
                float g01 = __uint_as_float(gv.y << 16);
                float g11 = __uint_as_float(gv.y & 0xffff0000u);
                float v0 = fmaf(pj, g10 - g00, g00);
                float v1 = fmaf(pj, g11 - g01, g01);
                acc0 += valid ? v0 : 0.0f;
                acc1 += valid ? v1 : 0.0f;
            }
        }

        // reduce the 3 slots into lanes 0..19
        float s0a = __shfl(acc0, lane + 20), s0b = __shfl(acc0, (lane + 40) & 63);
        float s1a = __shfl(acc1, lane + 20), s1b = __shfl(acc1, (lane + 40) & 63);
        acc0 += s0a + s0b;
        acc1 += s1a + s1b;

        asm volatile("" ::: "memory");
        if (lane < 20) {
            scr[w][2 * m]     = acc0;
            scr[w][2 * m + 1] = acc1;
        }
        asm volatile("" ::: "memory");

        float inv = 1.0f / fmaxf((float)c, 1.0f);
        float r = 0.0f;
        if (lane < OUTC)
            r = fmaf(scr[w][lane], inv, rt[(size_t)n * OUTC + lane]);

        float mx = (lane < OUTC) ? r : -1e30f;
#pragma unroll
        for (int off = 32; off > 0; off >>= 1) mx = fmaxf(mx, __shfl_xor(mx, off));
        float ex = (lane < OUTC) ? expf(r - mx) : 0.0f;
#pragma unroll
        for (int off = 32; off > 0; off >>= 1) ex += __shfl_xor(ex, off);
        float lse = mx + logf(ex);

        if (lane < OUTC) out[(size_t)n * OUTC + lane] = r - lse;
    }
}

// ---------------------------------------------------------------------------
extern "C" void kernel_launch(void* const* d_in, const int* in_sizes, int n_in,
                              void* d_out, int out_size, void* d_ws, size_t ws_size,
                              hipStream_t stream)
{
    const float* x     = (const float*)d_in[0];
    const int*   ei    = (const int*)  d_in[1];
    const float* ea    = (const float*)d_in[2];
    const float* W1    = (const float*)d_in[3];
    const float* root1 = (const float*)d_in[4];
    const float* b1    = (const float*)d_in[5];
    const float* W2    = (const float*)d_in[6];
    const float* root2 = (const float*)d_in[7];
    const float* b2    = (const float*)d_in[8];
    float* out = (float*)d_out;

    const int* src = ei;
    const int* dst = ei + NE;

    // workspace layout (71.6 MB total)
    char* wsp = (char*)d_ws;
    int*  cnt    = (int*)wsp;  wsp += sizeof(int) * NN;
    int*  offs   = (int*)wsp;  wsp += sizeof(int) * NN;
    int*  cursor = (int*)wsp;  wsp += sizeof(int) * NN;
    int*  bsum   = (int*)wsp;  wsp += sizeof(int) * 256;
    int2* pay    = (int2*)wsp; wsp += sizeof(int2) * NE;                        // 12.8 MB
    float* h     = (float*)wsp; wsp += sizeof(float) * (size_t)NN * HID;        // 25.6 MB
    unsigned* hw2b = (unsigned*)wsp; wsp += sizeof(unsigned) * (size_t)NN * 40; // 16 MB
    float* rt    = (float*)wsp; wsp += sizeof(float) * (size_t)NN * OUTC;       // 16 MB

    hipMemsetAsync(cnt, 0, sizeof(int) * NN, stream);

    int nb = (NN + 511) / 512;
    k_hist   <<<NE / 256, 256, 0, stream>>>(dst, cnt);
    k_scan1  <<<nb, 512, 0, stream>>>(cnt, bsum);
    k_scan2  <<<1, 64, 0, stream>>>(bsum, nb);
    k_scan3  <<<nb, 512, 0, stream>>>(cnt, bsum, offs, cursor);
    k_scatter<<<NE / 256, 256, 0, stream>>>(src, dst, ea, cursor, pay);

    k_agg1h  <<<2048, 256, 0, stream>>>(x, pay, offs, cnt, W1, root1, b1, h);
    k_hw2    <<<(NN + 255) / 256, 256, 0, stream>>>(h, W2, root2, b2, hw2b, rt);
    k_agg2f  <<<2048, 256, 0, stream>>>(hw2b, rt, pay, offs, cnt, out);
}

// Round 5
// 414.422 us; speedup vs baseline: 2.2742x; 1.1283x over previous
//
#include <hip/hip_runtime.h>
#include <math.h>

#define NN   100000
#define NE   1600000
#define INC  32
#define HID  64
#define OUTC 40

// bf16 helpers (round-to-nearest-even)
__device__ inline unsigned f2bf(float f) {
    unsigned u = __float_as_uint(f);
    return (u + 0x7fffu + ((u >> 16) & 1u)) >> 16;
}
__device__ inline unsigned packbf(float a, float b) {
    return f2bf(a) | (f2bf(b) << 16);
}
__device__ inline float bflo(unsigned u) { return __uint_as_float(u << 16); }
__device__ inline float bfhi(unsigned u) { return __uint_as_float(u & 0xffff0000u); }

// ---------------------------------------------------------------------------
// CSR build
// ---------------------------------------------------------------------------
__global__ __launch_bounds__(256) void k_hist(const int* __restrict__ dst,
                                              int* __restrict__ cnt)
{
    int e = blockIdx.x * 256 + threadIdx.x;
    atomicAdd(&cnt[dst[e]], 1);
}

__global__ __launch_bounds__(512) void k_scan1(const int* __restrict__ cnt,
                                               int* __restrict__ bsum)
{
    __shared__ int red[512];
    int i = blockIdx.x * 512 + threadIdx.x;
    red[threadIdx.x] = (i < NN) ? cnt[i] : 0;
    __syncthreads();
    for (int off = 256; off > 0; off >>= 1) {
        if (threadIdx.x < off) red[threadIdx.x] += red[threadIdx.x + off];
        __syncthreads();
    }
    if (threadIdx.x == 0) bsum[blockIdx.x] = red[0];
}

__global__ void k_scan2(int* bsum, int nb)
{
    if (threadIdx.x == 0) {
        int run = 0;
        for (int i = 0; i < nb; i++) { int v = bsum[i]; bsum[i] = run; run += v; }
    }
}

__global__ __launch_bounds__(512) void k_scan3(const int* __restrict__ cnt,
                                               const int* __restrict__ bsum,
                                               int* __restrict__ offs,
                                               int* __restrict__ cursor)
{
    __shared__ int tmp[512];
    int t = threadIdx.x;
    int i = blockIdx.x * 512 + t;
    int v = (i < NN) ? cnt[i] : 0;
    tmp[t] = v;
    __syncthreads();
    for (int off = 1; off < 512; off <<= 1) {
        int add = (t >= off) ? tmp[t - off] : 0;
        __syncthreads();
        tmp[t] += add;
        __syncthreads();
    }
    int excl = tmp[t] - v;
    if (i < NN) {
        int o = bsum[blockIdx.x] + excl;
        offs[i] = o;
        cursor[i] = o;
    }
}

__global__ __launch_bounds__(256) void k_scatter(const int* __restrict__ src,
                                                 const int* __restrict__ dst,
                                                 const float* __restrict__ pseudo,
                                                 int* __restrict__ cursor,
                                                 int2* __restrict__ pay)
{
    int e = blockIdx.x * 256 + threadIdx.x;
    int d = dst[e];
    int pos = atomicAdd(&cursor[d], 1);
    pay[pos] = make_int2(src[e], __float_as_int(pseudo[e]));
}

// ---------------------------------------------------------------------------
// Convert x to bf16-packed rows (16 uints / 64 B per node)
// ---------------------------------------------------------------------------
__global__ __launch_bounds__(256) void k_xb(const float* __restrict__ x,
                                            unsigned* __restrict__ xb)
{
    int i = blockIdx.x * 256 + threadIdx.x;   // NN*INC/2 = 1.6M, divisible by 256? 1.6e6/256=6250 exactly
    if (i >= NN * INC / 2) return;
    float2 v = ((const float2*)x)[i];
    xb[i] = packbf(v.x, v.y);
}

// ---------------------------------------------------------------------------
// Layer 1 gather-only: wave per node, 8 edges per vmem instruction.
// lane = slot*8+sub; slot = edge slot (0..7); sub covers feats sub*4..+3 (uint2).
// Writes A[n][0:32]=sum((1-p)x), A[n][32:64]=sum(p*x).
// ---------------------------------------------------------------------------
__global__ __launch_bounds__(256) void k_agg1(
    const unsigned* __restrict__ xb, const int2* __restrict__ pay,
    const int* __restrict__ offs, const int* __restrict__ cnt,
    float* __restrict__ A)
{
    int t = threadIdx.x;
    int w = t >> 6, lane = t & 63;
    int slot = lane >> 3, sub = lane & 7;

    for (int n0 = blockIdx.x * 4; n0 < NN; n0 += gridDim.x * 4) {
        int n = n0 + w;
        int e0 = offs[n], c = cnt[n];

        float a0[4] = {0.f, 0.f, 0.f, 0.f};
        float a1[4] = {0.f, 0.f, 0.f, 0.f};

        for (int base = 0; base < c; base += 64) {
            int bc = min(c - base, 64);
            int li = (lane < bc) ? lane : (bc - 1);
            int2 pl = pay[e0 + base + li];
            for (int g = 0; g < bc; g += 8) {
                int je = g + slot;                      // <= 63
                int   sj = __shfl(pl.x, je);
                float pj = __int_as_float(__shfl(pl.y, je));
                bool valid = je < bc;
                float w1v = valid ? pj : 0.0f;
                float w0v = valid ? (1.0f - pj) : 0.0f;
                uint2 gv = *((const uint2*)(xb + (size_t)sj * (INC / 2)) + sub);
                float f0 = bflo(gv.x), f1 = bfhi(gv.x);
                float f2 = bflo(gv.y), f3 = bfhi(gv.y);
                a0[0] = fmaf(w0v, f0, a0[0]); a0[1] = fmaf(w0v, f1, a0[1]);
                a0[2] = fmaf(w0v, f2, a0[2]); a0[3] = fmaf(w0v, f3, a0[3]);
                a1[0] = fmaf(w1v, f0, a1[0]); a1[1] = fmaf(w1v, f1, a1[1]);
                a1[2] = fmaf(w1v, f2, a1[2]); a1[3] = fmaf(w1v, f3, a1[3]);
            }
        }

        // reduce 8 slots (lane bits 3..5)
#pragma unroll
        for (int mask = 8; mask <= 32; mask <<= 1) {
#pragma unroll
            for (int j = 0; j < 4; j++) {
                a0[j] += __shfl_xor(a0[j], mask);
                a1[j] += __shfl_xor(a1[j], mask);
            }
        }
        if (slot == 0) {
            ((float4*)(A + (size_t)n * 64))[sub] =
                make_float4(a0[0], a0[1], a0[2], a0[3]);
            ((float4*)(A + (size_t)n * 64 + 32))[sub] =
                make_float4(a1[0], a1[1], a1[2], a1[3]);
        }
    }
}

// ---------------------------------------------------------------------------
// Node transform (merged): h = ELU((A@[W1_0;W1_1])/cnt + x@root1 + b1) in regs,
// then hw2b[n] = bf16 interleaved (g0,g1) pairs (g_k = h@W2[k]) and
// rt[n] = h@root2 + b2. One thread per node.
// ---------------------------------------------------------------------------
__global__ __launch_bounds__(256) void k_node(
    const float* __restrict__ A, const float* __restrict__ x,
    const int* __restrict__ cnt,
    const float* __restrict__ W1, const float* __restrict__ root1,
    const float* __restrict__ b1, const float* __restrict__ W2,
    const float* __restrict__ root2, const float* __restrict__ b2,
    unsigned* __restrict__ hw2b, float* __restrict__ rt)
{
    __shared__ float sW0[INC * HID], sW1[INC * HID], sR1[INC * HID], sb1[HID];
    __shared__ float sW2a[HID * OUTC], sW2b[HID * OUTC], sR2[HID * OUTC];
    __shared__ float sb2[OUTC];
    int t = threadIdx.x;
    for (int i = t; i < INC * HID; i += 256) {
        sW0[i] = W1[i];
        sW1[i] = W1[INC * HID + i];
        sR1[i] = root1[i];
    }
    for (int i = t; i < HID * OUTC; i += 256) {
        sW2a[i] = W2[i];
        sW2b[i] = W2[HID * OUTC + i];
        sR2[i]  = root2[i];
    }
    if (t < HID)  sb1[t] = b1[t];
    if (t < OUTC) sb2[t] = b2[t];
    __syncthreads();

    int n = blockIdx.x * 256 + t;
    if (n >= NN) return;

    float h[HID];
#pragma unroll
    for (int o = 0; o < HID; o++) h[o] = 0.0f;

    const float4* Ar = (const float4*)(A + (size_t)n * 64);
    for (int f4 = 0; f4 < 8; f4++) {
        float4 q0 = Ar[f4], q1 = Ar[8 + f4];
        float u0[4] = {q0.x, q0.y, q0.z, q0.w};
        float u1[4] = {q1.x, q1.y, q1.z, q1.w};
#pragma unroll
        for (int j = 0; j < 4; j++) {
            int f = f4 * 4 + j;
            const float* w0 = sW0 + f * HID;
            const float* w1 = sW1 + f * HID;
#pragma unroll
            for (int o = 0; o < HID; o++)
                h[o] = fmaf(u0[j], w0[o], fmaf(u1[j], w1[o], h[o]));
        }
    }

    float inv = 1.0f / fmaxf((float)cnt[n], 1.0f);
#pragma unroll
    for (int o = 0; o < HID; o++) h[o] *= inv;

    const float4* xr = (const float4*)(x + (size_t)n * INC);
    for (int f4 = 0; f4 < 8; f4++) {
        float4 q = xr[f4];
        float u[4] = {q.x, q.y, q.z, q.w};
#pragma unroll
        for (int j = 0; j < 4; j++) {
            const float* wr = sR1 + (f4 * 4 + j) * HID;
#pragma unroll
            for (int o = 0; o < HID; o++) h[o] = fmaf(u[j], wr[o], h[o]);
        }
    }
#pragma unroll
    for (int o = 0; o < HID; o++) {
        float v = h[o] + sb1[o];
        h[o] = (v > 0.0f) ? v : (expf(v) - 1.0f);
    }

    // hw2b in chunks of 8 outputs (keeps VGPR low; h stays in registers)
    uint2* gp = (uint2*)(hw2b + (size_t)n * 40);
#pragma unroll
    for (int c0 = 0; c0 < OUTC; c0 += 8) {
        float a0[8], a1[8];
#pragma unroll
        for (int j = 0; j < 8; j++) { a0[j] = 0.0f; a1[j] = 0.0f; }
        for (int f = 0; f < HID; f++) {
            const float* w0 = sW2a + f * OUTC + c0;
            const float* w1 = sW2b + f * OUTC + c0;
#pragma unroll
            for (int j = 0; j < 8; j++) {
                a0[j] = fmaf(h[f], w0[j], a0[j]);
                a1[j] = fmaf(h[f], w1[j], a1[j]);
            }
        }
#pragma unroll
        for (int j = 0; j < 8; j += 2)
            gp[(c0 + j) >> 1] = make_uint2(packbf(a0[j], a1[j]),
                                           packbf(a0[j + 1], a1[j + 1]));
    }

    // rt = h @ root2 + b2
    float4* rp = (float4*)(rt + (size_t)n * OUTC);
#pragma unroll
    for (int c0 = 0; c0 < OUTC; c0 += 8) {
        float ar[8];
#pragma unroll
        for (int j = 0; j < 8; j++) ar[j] = sb2[c0 + j];
        for (int f = 0; f < HID; f++) {
            const float* wr = sR2 + f * OUTC + c0;
#pragma unroll
            for (int j = 0; j < 8; j++) ar[j] = fmaf(h[f], wr[j], ar[j]);
        }
        rp[c0 >> 2]       = make_float4(ar[0], ar[1], ar[2], ar[3]);
        rp[(c0 >> 2) + 1] = make_float4(ar[4], ar[5], ar[6], ar[7]);
    }
}

// ---------------------------------------------------------------------------
// Layer 2: wave per node, 6 edges per vmem instruction (10 lanes x uint4 each
// = 8 bf16 = outputs 4m..4m+3, both knots). Reduce 6 slots, + rt, log_softmax.
// ---------------------------------------------------------------------------
__global__ __launch_bounds__(256) void k_agg2f(
    const unsigned* __restrict__ hw2b, const float* __restrict__ rt,
    const int2* __restrict__ pay, const int* __restrict__ offs,
    const int* __restrict__ cnt, float* __restrict__ out)
{
    __shared__ float scr[4][OUTC];
    int t = threadIdx.x;
    int w = t >> 6, lane = t & 63;
    int slot = lane / 10;            // 0..5 active, 6 = idle lanes 60-63
    int m = lane - slot * 10;        // 0..9 -> outputs 4m..4m+3

    for (int n0 = blockIdx.x * 4; n0 < NN; n0 += gridDim.x * 4) {
        int n = n0 + w;
        int e0 = offs[n], c = cnt[n];

        float acc[4] = {0.f, 0.f, 0.f, 0.f};
        for (int base = 0; base < c; base += 64) {
            int bc = min(c - base, 64);
            int li = (lane < bc) ? lane : (bc - 1);
            int2 pl = pay[e0 + base + li];
            for (int g = 0; g < bc; g += 6) {
                int je = g + slot;
                int js = je & 63;
                int   sj = __shfl(pl.x, js);
                float pj = __int_as_float(__shfl(pl.y, js));
                bool valid = (slot < 6) && (je < bc);
                uint4 gv = *((const uint4*)(hw2b + (size_t)sj * 40) + m);
                float v0 = fmaf(pj, bfhi(gv.x) - bflo(gv.x), bflo(gv.x));
                float v1 = fmaf(pj, bfhi(gv.y) - bflo(gv.y), bflo(gv.y));
                float v2 = fmaf(pj, bfhi(gv.z) - bflo(gv.z), bflo(gv.z));
                float v3 = fmaf(pj, bfhi(gv.w) - bflo(gv.w), bflo(gv.w));
                acc[0] += valid ? v0 : 0.0f;
                acc[1] += valid ? v1 : 0.0f;
                acc[2] += valid ? v2 : 0.0f;
                acc[3] += valid ? v3 : 0.0f;
            }
        }

        // reduce 6 slots: round 1 folds slots 3..5 onto 0..2; round 2 folds 1,2 onto 0
#pragma unroll
        for (int j = 0; j < 4; j++) acc[j] += __shfl(acc[j], (lane + 30) & 63);
#pragma unroll
        for (int j = 0; j < 4; j++)
            acc[j] += __shfl(acc[j], (lane + 10) & 63) + __shfl(acc[j], (lane + 20) & 63);

        asm volatile("" ::: "memory");
        if (lane < 10) {
            scr[w][4 * m]     = acc[0];
            scr[w][4 * m + 1] = acc[1];
            scr[w][4 * m + 2] = acc[2];
            scr[w][4 * m + 3] = acc[3];
        }
        asm volatile("" ::: "memory");

        float inv = 1.0f / fmaxf((float)c, 1.0f);
        float r = 0.0f;
        if (lane < OUTC)
            r = fmaf(scr[w][lane], inv, rt[(size_t)n * OUTC + lane]);

        float mx = (lane < OUTC) ? r : -1e30f;
#pragma unroll
        for (int off = 32; off > 0; off >>= 1) mx = fmaxf(mx, __shfl_xor(mx, off));
        float ex = (lane < OUTC) ? expf(r - mx) : 0.0f;
#pragma unroll
        for (int off = 32; off > 0; off >>= 1) ex += __shfl_xor(ex, off);
        float lse = mx + logf(ex);

        if (lane < OUTC) out[(size_t)n * OUTC + lane] = r - lse;
    }
}

// ---------------------------------------------------------------------------
extern "C" void kernel_launch(void* const* d_in, const int* in_sizes, int n_in,
                              void* d_out, int out_size, void* d_ws, size_t ws_size,
                              hipStream_t stream)
{
    const float* x     = (const float*)d_in[0];
    const int*   ei    = (const int*)  d_in[1];
    const float* ea    = (const float*)d_in[2];
    const float* W1    = (const float*)d_in[3];
    const float* root1 = (const float*)d_in[4];
    const float* b1    = (const float*)d_in[5];
    const float* W2    = (const float*)d_in[6];
    const float* root2 = (const float*)d_in[7];
    const float* b2    = (const float*)d_in[8];
    float* out = (float*)d_out;

    const int* src = ei;
    const int* dst = ei + NE;

    // workspace layout (~78 MB total)
    char* wsp = (char*)d_ws;
    int*  cnt    = (int*)wsp;  wsp += sizeof(int) * NN;
    int*  offs   = (int*)wsp;  wsp += sizeof(int) * NN;
    int*  cursor = (int*)wsp;  wsp += sizeof(int) * NN;
    int*  bsum   = (int*)wsp;  wsp += sizeof(int) * 256;
    int2* pay    = (int2*)wsp; wsp += sizeof(int2) * NE;                          // 12.8 MB
    unsigned* xb = (unsigned*)wsp; wsp += sizeof(unsigned) * (size_t)NN * (INC/2);// 6.4 MB
    float* A     = (float*)wsp; wsp += sizeof(float) * (size_t)NN * 64;           // 25.6 MB
    unsigned* hw2b = (unsigned*)wsp; wsp += sizeof(unsigned) * (size_t)NN * 40;   // 16 MB
    float* rt    = (float*)wsp; wsp += sizeof(float) * (size_t)NN * OUTC;         // 16 MB

    hipMemsetAsync(cnt, 0, sizeof(int) * NN, stream);

    int nb = (NN + 511) / 512;
    k_xb     <<<(NN * INC / 2 + 255) / 256, 256, 0, stream>>>(x, xb);
    k_hist   <<<NE / 256, 256, 0, stream>>>(dst, cnt);
    k_scan1  <<<nb, 512, 0, stream>>>(cnt, bsum);
    k_scan2  <<<1, 64, 0, stream>>>(bsum, nb);
    k_scan3  <<<nb, 512, 0, stream>>>(cnt, bsum, offs, cursor);
    k_scatter<<<NE / 256, 256, 0, stream>>>(src, dst, ea, cursor, pay);

    k_agg1   <<<2048, 256, 0, stream>>>(xb, pay, offs, cnt, A);
    k_node   <<<(NN + 255) / 256, 256, 0, stream>>>(A, x, cnt, W1, root1, b1,
                                                    W2, root2, b2, hw2b, rt);
    k_agg2f  <<<2048, 256, 0, stream>>>(hw2b, rt, pay, offs, cnt, out);
}

// Round 6
// 367.155 us; speedup vs baseline: 2.5670x; 1.1287x over previous
//
#include <hip/hip_runtime.h>
#include <math.h>

#define NN   100000
#define NE   1600000
#define INC  32
#define HID  64
#define OUTC 40
#define NRANGE 8
#define NPR  (NN / NRANGE)       // 12500

// bf16 helpers (round-to-nearest-even)
__device__ inline unsigned f2bf(float f) {
    unsigned u = __float_as_uint(f);
    return (u + 0x7fffu + ((u >> 16) & 1u)) >> 16;
}
__device__ inline unsigned packbf(float a, float b) {
    return f2bf(a) | (f2bf(b) << 16);
}
__device__ inline float bflo(unsigned u) { return __uint_as_float(u << 16); }
__device__ inline float bfhi(unsigned u) { return __uint_as_float(u & 0xffff0000u); }

// payload decode: src in bits 0-16, p (15-bit fixed) in bits 17-31
__device__ inline int   pdec_s(unsigned v) { return (int)(v & 0x1FFFFu); }
__device__ inline float pdec_p(unsigned v) { return (float)(v >> 17) * (1.0f / 32767.0f); }

// ---------------------------------------------------------------------------
// CSR build
// ---------------------------------------------------------------------------
__global__ __launch_bounds__(256) void k_hist(const int* __restrict__ dst,
                                              int* __restrict__ cnt)
{
    int e = blockIdx.x * 256 + threadIdx.x;
    atomicAdd(&cnt[dst[e]], 1);
}

__global__ __launch_bounds__(512) void k_scan1(const int* __restrict__ cnt,
                                               int* __restrict__ bsum)
{
    __shared__ int red[512];
    int i = blockIdx.x * 512 + threadIdx.x;
    red[threadIdx.x] = (i < NN) ? cnt[i] : 0;
    __syncthreads();
    for (int off = 256; off > 0; off >>= 1) {
        if (threadIdx.x < off) red[threadIdx.x] += red[threadIdx.x + off];
        __syncthreads();
    }
    if (threadIdx.x == 0) bsum[blockIdx.x] = red[0];
}

__global__ void k_scan2(int* bsum, int nb)
{
    if (threadIdx.x == 0) {
        int run = 0;
        for (int i = 0; i < nb; i++) { int v = bsum[i]; bsum[i] = run; run += v; }
    }
}

__global__ __launch_bounds__(512) void k_scan3(const int* __restrict__ cnt,
                                               const int* __restrict__ bsum,
                                               int* __restrict__ offs,
                                               int* __restrict__ cursor)
{
    __shared__ int tmp[512];
    int t = threadIdx.x;
    int i = blockIdx.x * 512 + t;
    int v = (i < NN) ? cnt[i] : 0;
    tmp[t] = v;
    __syncthreads();
    for (int off = 1; off < 512; off <<= 1) {
        int add = (t >= off) ? tmp[t - off] : 0;
        __syncthreads();
        tmp[t] += add;
        __syncthreads();
    }
    int excl = tmp[t] - v;
    if (i < NN) {
        int o = bsum[blockIdx.x] + excl;
        offs[i] = o;
        cursor[i] = o;
    }
}

// Range-partitioned scatter: block id -> range (id&7), chunk (id>>3).
// With round-robin block->XCD mapping, each dst-range's writes stay in one
// XCD's L2 (0.8 MB region), written back once.
__global__ __launch_bounds__(256) void k_scatter8(
    const int* __restrict__ src, const int* __restrict__ dst,
    const float* __restrict__ pseudo,
    int* __restrict__ cursor, unsigned* __restrict__ pay)
{
    int r = blockIdx.x & 7;
    int chunk = blockIdx.x >> 3;
    int lo = r * NPR, hi = lo + NPR;
    int base = chunk * 2560;                 // NE / 2560 = 625 chunks exactly
#pragma unroll
    for (int i = 0; i < 10; i++) {
        int e = base + i * 256 + threadIdx.x;
        int d = dst[e];
        if (d >= lo && d < hi) {
            int pos = atomicAdd(&cursor[d], 1);
            unsigned pq = (unsigned)__float2int_rn(pseudo[e] * 32767.0f);
            pay[pos] = (unsigned)src[e] | (pq << 17);
        }
    }
}

// ---------------------------------------------------------------------------
// Convert x to bf16-packed rows (16 uints / 64 B per node)
// ---------------------------------------------------------------------------
__global__ __launch_bounds__(256) void k_xb(const float* __restrict__ x,
                                            unsigned* __restrict__ xb)
{
    int i = blockIdx.x * 256 + threadIdx.x;
    if (i >= NN * INC / 2) return;
    float2 v = ((const float2*)x)[i];
    xb[i] = packbf(v.x, v.y);
}

// ---------------------------------------------------------------------------
// Layer 1 gather-only: wave per node, 8 edges per vmem instruction.
// lane = slot*8+sub; slot = edge slot (0..7); sub covers feats sub*4..+3 (uint2).
// Writes A[n][0:32]=sum((1-p)x), A[n][32:64]=sum(p*x).
// ---------------------------------------------------------------------------
__global__ __launch_bounds__(256) void k_agg1(
    const unsigned* __restrict__ xb, const unsigned* __restrict__ pay,
    const int* __restrict__ offs, const int* __restrict__ cnt,
    float* __restrict__ A)
{
    int t = threadIdx.x;
    int w = t >> 6, lane = t & 63;
    int slot = lane >> 3, sub = lane & 7;

    for (int n0 = blockIdx.x * 4; n0 < NN; n0 += gridDim.x * 4) {
        int n = n0 + w;
        int e0 = offs[n], c = cnt[n];

        float a0[4] = {0.f, 0.f, 0.f, 0.f};
        float a1[4] = {0.f, 0.f, 0.f, 0.f};

        for (int base = 0; base < c; base += 64) {
            int bc = min(c - base, 64);
            int li = (lane < bc) ? lane : (bc - 1);
            unsigned pl = pay[e0 + base + li];
            for (int g = 0; g < bc; g += 8) {
                int je = g + slot;                      // <= 63
                unsigned v = (unsigned)__shfl((int)pl, je);
                int   sj = pdec_s(v);
                float pj = pdec_p(v);
                bool valid = je < bc;
                float w1v = valid ? pj : 0.0f;
                float w0v = valid ? (1.0f - pj) : 0.0f;
                uint2 gv = *((const uint2*)(xb + (size_t)sj * (INC / 2)) + sub);
                float f0 = bflo(gv.x), f1 = bfhi(gv.x);
                float f2 = bflo(gv.y), f3 = bfhi(gv.y);
                a0[0] = fmaf(w0v, f0, a0[0]); a0[1] = fmaf(w0v, f1, a0[1]);
                a0[2] = fmaf(w0v, f2, a0[2]); a0[3] = fmaf(w0v, f3, a0[3]);
                a1[0] = fmaf(w1v, f0, a1[0]); a1[1] = fmaf(w1v, f1, a1[1]);
                a1[2] = fmaf(w1v, f2, a1[2]); a1[3] = fmaf(w1v, f3, a1[3]);
            }
        }

        // reduce 8 slots (lane bits 3..5)
#pragma unroll
        for (int mask = 8; mask <= 32; mask <<= 1) {
#pragma unroll
            for (int j = 0; j < 4; j++) {
                a0[j] += __shfl_xor(a0[j], mask);
                a1[j] += __shfl_xor(a1[j], mask);
            }
        }
        if (slot == 0) {
            ((float4*)(A + (size_t)n * 64))[sub] =
                make_float4(a0[0], a0[1], a0[2], a0[3]);
            ((float4*)(A + (size_t)n * 64 + 32))[sub] =
                make_float4(a1[0], a1[1], a1[2], a1[3]);
        }
    }
}

// ---------------------------------------------------------------------------
// Node transform (merged): h = ELU((A@[W1_0;W1_1])/cnt + x@root1 + b1) in regs,
// then hw2b[n] = bf16 interleaved (g0,g1) pairs (g_k = h@W2[k]) and
// rt[n] = h@root2 + b2. One thread per node.
// ---------------------------------------------------------------------------
__global__ __launch_bounds__(256) void k_node(
    const float* __restrict__ A, const float* __restrict__ x,
    const int* __restrict__ cnt,
    const float* __restrict__ W1, const float* __restrict__ root1,
    const float* __restrict__ b1, const float* __restrict__ W2,
    const float* __restrict__ root2, const float* __restrict__ b2,
    unsigned* __restrict__ hw2b, float* __restrict__ rt)
{
    __shared__ float sW0[INC * HID], sW1[INC * HID], sR1[INC * HID], sb1[HID];
    __shared__ float sW2a[HID * OUTC], sW2b[HID * OUTC], sR2[HID * OUTC];
    __shared__ float sb2[OUTC];
    int t = threadIdx.x;
    for (int i = t; i < INC * HID; i += 256) {
        sW0[i] = W1[i];
        sW1[i] = W1[INC * HID + i];
        sR1[i] = root1[i];
    }
    for (int i = t; i < HID * OUTC; i += 256) {
        sW2a[i] = W2[i];
        sW2b[i] = W2[HID * OUTC + i];
        sR2[i]  = root2[i];
    }
    if (t < HID)  sb1[t] = b1[t];
    if (t < OUTC) sb2[t] = b2[t];
    __syncthreads();

    int n = blockIdx.x * 256 + t;
    if (n >= NN) return;

    float h[HID];
#pragma unroll
    for (int o = 0; o < HID; o++) h[o] = 0.0f;

    const float4* Ar = (const float4*)(A + (size_t)n * 64);
    for (int f4 = 0; f4 < 8; f4++) {
        float4 q0 = Ar[f4], q1 = Ar[8 + f4];
        float u0[4] = {q0.x, q0.y, q0.z, q0.w};
        float u1[4] = {q1.x, q1.y, q1.z, q1.w};
#pragma unroll
        for (int j = 0; j < 4; j++) {
            int f = f4 * 4 + j;
            const float* w0 = sW0 + f * HID;
            const float* w1 = sW1 + f * HID;
#pragma unroll
            for (int o = 0; o < HID; o++)
                h[o] = fmaf(u0[j], w0[o], fmaf(u1[j], w1[o], h[o]));
        }
    }

    float inv = 1.0f / fmaxf((float)cnt[n], 1.0f);
#pragma unroll
    for (int o = 0; o < HID; o++) h[o] *= inv;

    const float4* xr = (const float4*)(x + (size_t)n * INC);
    for (int f4 = 0; f4 < 8; f4++) {
        float4 q = xr[f4];
        float u[4] = {q.x, q.y, q.z, q.w};
#pragma unroll
        for (int j = 0; j < 4; j++) {
            const float* wr = sR1 + (f4 * 4 + j) * HID;
#pragma unroll
            for (int o = 0; o < HID; o++) h[o] = fmaf(u[j], wr[o], h[o]);
        }
    }
#pragma unroll
    for (int o = 0; o < HID; o++) {
        float v = h[o] + sb1[o];
        h[o] = (v > 0.0f) ? v : (expf(v) - 1.0f);
    }

    // hw2b in chunks of 8 outputs (keeps VGPR low; h stays in registers)
    uint2* gp = (uint2*)(hw2b + (size_t)n * 40);
#pragma unroll
    for (int c0 = 0; c0 < OUTC; c0 += 8) {
        float a0[8], a1[8];
#pragma unroll
        for (int j = 0; j < 8; j++) { a0[j] = 0.0f; a1[j] = 0.0f; }
        for (int f = 0; f < HID; f++) {
            const float* w0 = sW2a + f * OUTC + c0;
            const float* w1 = sW2b + f * OUTC + c0;
#pragma unroll
            for (int j = 0; j < 8; j++) {
                a0[j] = fmaf(h[f], w0[j], a0[j]);
                a1[j] = fmaf(h[f], w1[j], a1[j]);
            }
        }
#pragma unroll
        for (int j = 0; j < 8; j += 2)
            gp[(c0 + j) >> 1] = make_uint2(packbf(a0[j], a1[j]),
                                           packbf(a0[j + 1], a1[j + 1]));
    }

    // rt = h @ root2 + b2
    float4* rp = (float4*)(rt + (size_t)n * OUTC);
#pragma unroll
    for (int c0 = 0; c0 < OUTC; c0 += 8) {
        float ar[8];
#pragma unroll
        for (int j = 0; j < 8; j++) ar[j] = sb2[c0 + j];
        for (int f = 0; f < HID; f++) {
            const float* wr = sR2 + f * OUTC + c0;
#pragma unroll
            for (int j = 0; j < 8; j++) ar[j] = fmaf(h[f], wr[j], ar[j]);
        }
        rp[c0 >> 2]       = make_float4(ar[0], ar[1], ar[2], ar[3]);
        rp[(c0 >> 2) + 1] = make_float4(ar[4], ar[5], ar[6], ar[7]);
    }
}

// ---------------------------------------------------------------------------
// Layer 2: wave per node, 6 edges per vmem instruction (10 lanes x uint4 each
// = 8 bf16 = outputs 4m..4m+3, both knots). Reduce 6 slots, + rt, log_softmax.
// ---------------------------------------------------------------------------
__global__ __launch_bounds__(256) void k_agg2f(
    const unsigned* __restrict__ hw2b, const float* __restrict__ rt,
    const unsigned* __restrict__ pay, const int* __restrict__ offs,
    const int* __restrict__ cnt, float* __restrict__ out)
{
    __shared__ float scr[4][OUTC];
    int t = threadIdx.x;
    int w = t >> 6, lane = t & 63;
    int slot = lane / 10;            // 0..5 active, 6 = idle lanes 60-63
    int m = lane - slot * 10;        // 0..9 -> outputs 4m..4m+3

    for (int n0 = blockIdx.x * 4; n0 < NN; n0 += gridDim.x * 4) {
        int n = n0 + w;
        int e0 = offs[n], c = cnt[n];

        float acc[4] = {0.f, 0.f, 0.f, 0.f};
        for (int base = 0; base < c; base += 64) {
            int bc = min(c - base, 64);
            int li = (lane < bc) ? lane : (bc - 1);
            unsigned pl = pay[e0 + base + li];
            for (int g = 0; g < bc; g += 6) {
                int je = g + slot;
                int js = je & 63;
                unsigned v = (unsigned)__shfl((int)pl, js);
                int   sj = pdec_s(v);
                float pj = pdec_p(v);
                bool valid = (slot < 6) && (je < bc);
                uint4 gv = *((const uint4*)(hw2b + (size_t)sj * 40) + m);
                float v0 = fmaf(pj, bfhi(gv.x) - bflo(gv.x), bflo(gv.x));
                float v1 = fmaf(pj, bfhi(gv.y) - bflo(gv.y), bflo(gv.y));
                float v2 = fmaf(pj, bfhi(gv.z) - bflo(gv.z), bflo(gv.z));
                float v3 = fmaf(pj, bfhi(gv.w) - bflo(gv.w), bflo(gv.w));
                acc[0] += valid ? v0 : 0.0f;
                acc[1] += valid ? v1 : 0.0f;
                acc[2] += valid ? v2 : 0.0f;
                acc[3] += valid ? v3 : 0.0f;
            }
        }

        // reduce 6 slots: round 1 folds slots 3..5 onto 0..2; round 2 folds 1,2 onto 0
#pragma unroll
        for (int j = 0; j < 4; j++) acc[j] += __shfl(acc[j], (lane + 30) & 63);
#pragma unroll
        for (int j = 0; j < 4; j++)
            acc[j] += __shfl(acc[j], (lane + 10) & 63) + __shfl(acc[j], (lane + 20) & 63);

        asm volatile("" ::: "memory");
        if (lane < 10) {
            scr[w][4 * m]     = acc[0];
            scr[w][4 * m + 1] = acc[1];
            scr[w][4 * m + 2] = acc[2];
            scr[w][4 * m + 3] = acc[3];
        }
        asm volatile("" ::: "memory");

        float inv = 1.0f / fmaxf((float)c, 1.0f);
        float r = 0.0f;
        if (lane < OUTC)
            r = fmaf(scr[w][lane], inv, rt[(size_t)n * OUTC + lane]);

        float mx = (lane < OUTC) ? r : -1e30f;
#pragma unroll
        for (int off = 32; off > 0; off >>= 1) mx = fmaxf(mx, __shfl_xor(mx, off));
        float ex = (lane < OUTC) ? expf(r - mx) : 0.0f;
#pragma unroll
        for (int off = 32; off > 0; off >>= 1) ex += __shfl_xor(ex, off);
        float lse = mx + logf(ex);

        if (lane < OUTC) out[(size_t)n * OUTC + lane] = r - lse;
    }
}

// ---------------------------------------------------------------------------
extern "C" void kernel_launch(void* const* d_in, const int* in_sizes, int n_in,
                              void* d_out, int out_size, void* d_ws, size_t ws_size,
                              hipStream_t stream)
{
    const float* x     = (const float*)d_in[0];
    const int*   ei    = (const int*)  d_in[1];
    const float* ea    = (const float*)d_in[2];
    const float* W1    = (const float*)d_in[3];
    const float* root1 = (const float*)d_in[4];
    const float* b1    = (const float*)d_in[5];
    const float* W2    = (const float*)d_in[6];
    const float* root2 = (const float*)d_in[7];
    const float* b2    = (const float*)d_in[8];
    float* out = (float*)d_out;

    const int* src = ei;
    const int* dst = ei + NE;

    // workspace layout (~72 MB total)
    char* wsp = (char*)d_ws;
    int*  cnt    = (int*)wsp;  wsp += sizeof(int) * NN;
    int*  offs   = (int*)wsp;  wsp += sizeof(int) * NN;
    int*  cursor = (int*)wsp;  wsp += sizeof(int) * NN;
    int*  bsum   = (int*)wsp;  wsp += sizeof(int) * 256;
    unsigned* pay = (unsigned*)wsp; wsp += sizeof(unsigned) * NE;                 // 6.4 MB
    unsigned* xb = (unsigned*)wsp; wsp += sizeof(unsigned) * (size_t)NN * (INC/2);// 6.4 MB
    float* A     = (float*)wsp; wsp += sizeof(float) * (size_t)NN * 64;           // 25.6 MB
    unsigned* hw2b = (unsigned*)wsp; wsp += sizeof(unsigned) * (size_t)NN * 40;   // 16 MB
    float* rt    = (float*)wsp; wsp += sizeof(float) * (size_t)NN * OUTC;         // 16 MB

    hipMemsetAsync(cnt, 0, sizeof(int) * NN, stream);

    int nb = (NN + 511) / 512;
    k_xb      <<<(NN * INC / 2 + 255) / 256, 256, 0, stream>>>(x, xb);
    k_hist    <<<NE / 256, 256, 0, stream>>>(dst, cnt);
    k_scan1   <<<nb, 512, 0, stream>>>(cnt, bsum);
    k_scan2   <<<1, 64, 0, stream>>>(bsum, nb);
    k_scan3   <<<nb, 512, 0, stream>>>(cnt, bsum, offs, cursor);
    k_scatter8<<<(NE / 2560) * 8, 256, 0, stream>>>(src, dst, ea, cursor, pay);

    k_agg1    <<<2048, 256, 0, stream>>>(xb, pay, offs, cnt, A);
    k_node    <<<(NN + 255) / 256, 256, 0, stream>>>(A, x, cnt, W1, root1, b1,
                                                     W2, root2, b2, hw2b, rt);
    k_agg2f   <<<2048, 256, 0, stream>>>(hw2b, rt, pay, offs, cnt, out);
}

// Round 7
// 295.799 us; speedup vs baseline: 3.1862x; 1.2412x over previous
//
#include <hip/hip_runtime.h>
#include <math.h>

#define NN   100000
#define NE   1600000
#define INC  32
#define HID  64
#define OUTC 40
#define NRANGE 8
#define NPR  (NN / NRANGE)       // 12500

typedef short bf16x8 __attribute__((ext_vector_type(8)));
typedef float f32x4  __attribute__((ext_vector_type(4)));

// bf16 helpers (round-to-nearest-even)
__device__ inline unsigned f2bf(float f) {
    unsigned u = __float_as_uint(f);
    return (u + 0x7fffu + ((u >> 16) & 1u)) >> 16;
}
__device__ inline unsigned packbf(float a, float b) {
    return f2bf(a) | (f2bf(b) << 16);
}
__device__ inline float bflo(unsigned u) { return __uint_as_float(u << 16); }
__device__ inline float bfhi(unsigned u) { return __uint_as_float(u & 0xffff0000u); }

// payload decode: src in bits 0-16, p (15-bit fixed) in bits 17-31
__device__ inline int   pdec_s(unsigned v) { return (int)(v & 0x1FFFFu); }
__device__ inline float pdec_p(unsigned v) { return (float)(v >> 17) * (1.0f / 32767.0f); }

// ---------------------------------------------------------------------------
// CSR build
// ---------------------------------------------------------------------------
__global__ __launch_bounds__(256) void k_hist(const int* __restrict__ dst,
                                              int* __restrict__ cnt)
{
    int e = blockIdx.x * 256 + threadIdx.x;
    atomicAdd(&cnt[dst[e]], 1);
}

__global__ __launch_bounds__(512) void k_scan1(const int* __restrict__ cnt,
                                               int* __restrict__ bsum)
{
    __shared__ int red[512];
    int i = blockIdx.x * 512 + threadIdx.x;
    red[threadIdx.x] = (i < NN) ? cnt[i] : 0;
    __syncthreads();
    for (int off = 256; off > 0; off >>= 1) {
        if (threadIdx.x < off) red[threadIdx.x] += red[threadIdx.x + off];
        __syncthreads();
    }
    if (threadIdx.x == 0) bsum[blockIdx.x] = red[0];
}

__global__ void k_scan2(int* bsum, int nb)
{
    if (threadIdx.x == 0) {
        int run = 0;
        for (int i = 0; i < nb; i++) { int v = bsum[i]; bsum[i] = run; run += v; }
    }
}

__global__ __launch_bounds__(512) void k_scan3(const int* __restrict__ cnt,
                                               const int* __restrict__ bsum,
                                               int* __restrict__ offs,
                                               int* __restrict__ cursor)
{
    __shared__ int tmp[512];
    int t = threadIdx.x;
    int i = blockIdx.x * 512 + t;
    int v = (i < NN) ? cnt[i] : 0;
    tmp[t] = v;
    __syncthreads();
    for (int off = 1; off < 512; off <<= 1) {
        int add = (t >= off) ? tmp[t - off] : 0;
        __syncthreads();
        tmp[t] += add;
        __syncthreads();
    }
    int excl = tmp[t] - v;
    if (i < NN) {
        int o = bsum[blockIdx.x] + excl;
        offs[i] = o;
        cursor[i] = o;
    }
}

// Range-partitioned scatter (keeps each dst-range's writes in one XCD's L2)
__global__ __launch_bounds__(256) void k_scatter8(
    const int* __restrict__ src, const int* __restrict__ dst,
    const float* __restrict__ pseudo,
    int* __restrict__ cursor, unsigned* __restrict__ pay)
{
    int r = blockIdx.x & 7;
    int chunk = blockIdx.x >> 3;
    int lo = r * NPR, hi = lo + NPR;
    int base = chunk * 2560;
#pragma unroll
    for (int i = 0; i < 10; i++) {
        int e = base + i * 256 + threadIdx.x;
        int d = dst[e];
        if (d >= lo && d < hi) {
            int pos = atomicAdd(&cursor[d], 1);
            unsigned pq = (unsigned)__float2int_rn(pseudo[e] * 32767.0f);
            pay[pos] = (unsigned)src[e] | (pq << 17);
        }
    }
}

// ---------------------------------------------------------------------------
// x -> bf16 packed rows
// ---------------------------------------------------------------------------
__global__ __launch_bounds__(256) void k_xb(const float* __restrict__ x,
                                            unsigned* __restrict__ xb)
{
    int i = blockIdx.x * 256 + threadIdx.x;
    if (i >= NN * INC / 2) return;
    float2 v = ((const float2*)x)[i];
    xb[i] = packbf(v.x, v.y);
}

// ---------------------------------------------------------------------------
// Weight prep: W1T[64][96] = [W1_0; W1_1; root1]^T (bf16, o-major)
//              W2T[128][64]: row j<80: j=2o+khat -> W2[khat][:,o]; 80..119:
//              root2[:, j-80]; 120..127: 0.  (bf16, col(j)-major)
// ---------------------------------------------------------------------------
__global__ __launch_bounds__(256) void k_wprep(
    const float* __restrict__ W1, const float* __restrict__ root1,
    const float* __restrict__ W2, const float* __restrict__ root2,
    ushort* __restrict__ W1T, ushort* __restrict__ W2T)
{
    int i = blockIdx.x * 256 + threadIdx.x;
    if (i < 64 * 96) {
        int o = i / 96, k = i % 96;
        float v;
        if (k < 32)      v = W1[k * HID + o];
        else if (k < 64) v = W1[INC * HID + (k - 32) * HID + o];
        else             v = root1[(k - 64) * HID + o];
        W1T[i] = (ushort)f2bf(v);
    }
    int i2 = i - 64 * 96;
    if (i2 >= 0 && i2 < 128 * 64) {
        int j = i2 / 64, k = i2 % 64;
        float v = 0.0f;
        if (j < 80)       v = W2[(j & 1) * (HID * OUTC) + k * OUTC + (j >> 1)];
        else if (j < 120) v = root2[k * OUTC + (j - 80)];
        W2T[i2] = (ushort)f2bf(v);
    }
}

// ---------------------------------------------------------------------------
// Layer 1 gather: wave per node, 8 edges per vmem instruction.
// Emits Apre[n][96] bf16 = [sum((1-p)x)*inv | sum(p*x)*inv | x]
// ---------------------------------------------------------------------------
__global__ __launch_bounds__(256) void k_agg1(
    const unsigned* __restrict__ xb, const unsigned* __restrict__ pay,
    const int* __restrict__ offs, const int* __restrict__ cnt,
    ushort* __restrict__ Apre)
{
    int t = threadIdx.x;
    int w = t >> 6, lane = t & 63;
    int slot = lane >> 3, sub = lane & 7;

    for (int n0 = blockIdx.x * 4; n0 < NN; n0 += gridDim.x * 4) {
        int n = n0 + w;
        int e0 = offs[n], c = cnt[n];

        float a0[4] = {0.f, 0.f, 0.f, 0.f};
        float a1[4] = {0.f, 0.f, 0.f, 0.f};

        for (int base = 0; base < c; base += 64) {
            int bc = min(c - base, 64);
            int li = (lane < bc) ? lane : (bc - 1);
            unsigned pl = pay[e0 + base + li];
            for (int g = 0; g < bc; g += 8) {
                int je = g + slot;
                unsigned v = (unsigned)__shfl((int)pl, je);
                int   sj = pdec_s(v);
                float pj = pdec_p(v);
                bool valid = je < bc;
                float w1v = valid ? pj : 0.0f;
                float w0v = valid ? (1.0f - pj) : 0.0f;
                uint2 gv = *((const uint2*)(xb + (size_t)sj * (INC / 2)) + sub);
                float f0 = bflo(gv.x), f1 = bfhi(gv.x);
                float f2 = bflo(gv.y), f3 = bfhi(gv.y);
                a0[0] = fmaf(w0v, f0, a0[0]); a0[1] = fmaf(w0v, f1, a0[1]);
                a0[2] = fmaf(w0v, f2, a0[2]); a0[3] = fmaf(w0v, f3, a0[3]);
                a1[0] = fmaf(w1v, f0, a1[0]); a1[1] = fmaf(w1v, f1, a1[1]);
                a1[2] = fmaf(w1v, f2, a1[2]); a1[3] = fmaf(w1v, f3, a1[3]);
            }
        }
#pragma unroll
        for (int mask = 8; mask <= 32; mask <<= 1) {
#pragma unroll
            for (int j = 0; j < 4; j++) {
                a0[j] += __shfl_xor(a0[j], mask);
                a1[j] += __shfl_xor(a1[j], mask);
            }
        }
        if (slot == 0) {
            float inv = 1.0f / fmaxf((float)c, 1.0f);
            ushort* ap = Apre + (size_t)n * 96;
            *(uint2*)(ap + sub * 4) =
                make_uint2(packbf(a0[0] * inv, a0[1] * inv),
                           packbf(a0[2] * inv, a0[3] * inv));
            *(uint2*)(ap + 32 + sub * 4) =
                make_uint2(packbf(a1[0] * inv, a1[1] * inv),
                           packbf(a1[2] * inv, a1[3] * inv));
            uint2 xv = *((const uint2*)(xb + (size_t)n * 16) + sub);
            *(uint2*)(ap + 64 + sub * 4) = xv;
        }
    }
}

// ---------------------------------------------------------------------------
// Node transform on MFMA: 64 nodes/block, 4 waves x 16-node M-tiles.
// GEMM1: preH[64x64] = Apre[64x96] @ W1T^T  (+b1, ELU) -> h (bf16, LDS)
// GEMM2: G[64x128]   = h[64x64]   @ W2T^T  -> hw2b (bf16) + rt (f32,+b2)
// ---------------------------------------------------------------------------
__global__ __launch_bounds__(256) void k_node_mfma(
    const ushort* __restrict__ Apre, const ushort* __restrict__ W1T,
    const ushort* __restrict__ W2T, const float* __restrict__ b1,
    const float* __restrict__ b2,
    ushort* __restrict__ hw2b_us, float* __restrict__ rt)
{
    __shared__ ushort sA[64 * 104];
    __shared__ ushort sW1[64 * 104];
    __shared__ ushort sW2[128 * 72];
    __shared__ ushort sH[4 * 16 * 72];
    __shared__ float sb1[HID], sb2[OUTC];

    int t = threadIdx.x;
    int nbase = blockIdx.x * 64;

#pragma unroll
    for (int i = 0; i < 3; i++) {               // A: 64 rows x 12 uint4
        int idx = t + i * 256;
        int row = idx / 12, c = idx % 12;
        uint4 v = make_uint4(0, 0, 0, 0);
        if (nbase + row < NN)
            v = *(const uint4*)(Apre + (size_t)(nbase + row) * 96 + c * 8);
        *(uint4*)(sA + row * 104 + c * 8) = v;
    }
#pragma unroll
    for (int i = 0; i < 3; i++) {               // W1T: 64 x 12
        int idx = t + i * 256;
        int row = idx / 12, c = idx % 12;
        *(uint4*)(sW1 + row * 104 + c * 8) =
            *(const uint4*)(W1T + row * 96 + c * 8);
    }
#pragma unroll
    for (int i = 0; i < 4; i++) {               // W2T: 128 x 8
        int idx = t + i * 256;
        int row = idx / 8, c = idx % 8;
        *(uint4*)(sW2 + row * 72 + c * 8) =
            *(const uint4*)(W2T + row * 64 + c * 8);
    }
    if (t < HID) sb1[t] = b1[t];
    if (t >= 64 && t < 64 + OUTC) sb2[t - 64] = b2[t - 64];
    __syncthreads();

    int w = t >> 6, lane = t & 63;
    int lm = lane & 15, lk = lane >> 4;

    // GEMM1: wave w -> nodes [w*16, w*16+16), all 64 outs, K=96
    f32x4 acc[4];
#pragma unroll
    for (int nt = 0; nt < 4; nt++) acc[nt] = (f32x4){0.f, 0.f, 0.f, 0.f};
#pragma unroll
    for (int kk = 0; kk < 3; kk++) {
        bf16x8 af = *(const bf16x8*)(sA + (w * 16 + lm) * 104 + kk * 32 + lk * 8);
#pragma unroll
        for (int nt = 0; nt < 4; nt++) {
            bf16x8 bfr = *(const bf16x8*)(sW1 + (nt * 16 + lm) * 104 + kk * 32 + lk * 8);
            acc[nt] = __builtin_amdgcn_mfma_f32_16x16x32_bf16(af, bfr, acc[nt], 0, 0, 0);
        }
    }

    // epilogue 1: +b1, ELU, write h tile (wave-local)
    ushort* hrow = sH + w * 16 * 72;
#pragma unroll
    for (int nt = 0; nt < 4; nt++) {
#pragma unroll
        for (int r = 0; r < 4; r++) {
            float v = acc[nt][r] + sb1[nt * 16 + lm];
            v = (v > 0.0f) ? v : (expf(v) - 1.0f);
            hrow[(lk * 4 + r) * 72 + nt * 16 + lm] = (ushort)f2bf(v);
        }
    }
    asm volatile("" ::: "memory");

    // GEMM2: h[16x64] @ W2T^T -> 16 x 128, K=64
    f32x4 g[8];
#pragma unroll
    for (int nt = 0; nt < 8; nt++) g[nt] = (f32x4){0.f, 0.f, 0.f, 0.f};
#pragma unroll
    for (int kk = 0; kk < 2; kk++) {
        bf16x8 af = *(const bf16x8*)(hrow + lm * 72 + kk * 32 + lk * 8);
#pragma unroll
        for (int nt = 0; nt < 8; nt++) {
            bf16x8 bfr = *(const bf16x8*)(sW2 + (nt * 16 + lm) * 72 + kk * 32 + lk * 8);
            g[nt] = __builtin_amdgcn_mfma_f32_16x16x32_bf16(af, bfr, g[nt], 0, 0, 0);
        }
    }

    // epilogue 2: j<80 -> hw2b bf16; 80..119 -> rt f32 (+b2)
#pragma unroll
    for (int nt = 0; nt < 8; nt++) {
        int j = nt * 16 + lm;
#pragma unroll
        for (int r = 0; r < 4; r++) {
            int node = nbase + w * 16 + lk * 4 + r;
            if (node >= NN) continue;
            float v = g[nt][r];
            if (j < 80)
                hw2b_us[(size_t)node * 80 + j] = (ushort)f2bf(v);
            else if (j < 120)
                rt[(size_t)node * 40 + (j - 80)] = v + sb2[j - 80];
        }
    }
}

// ---------------------------------------------------------------------------
// Layer 2: wave per node, 6 edges per vmem instruction (10 lanes x uint4).
// ---------------------------------------------------------------------------
__global__ __launch_bounds__(256) void k_agg2f(
    const unsigned* __restrict__ hw2b, const float* __restrict__ rt,
    const unsigned* __restrict__ pay, const int* __restrict__ offs,
    const int* __restrict__ cnt, float* __restrict__ out)
{
    __shared__ float scr[4][OUTC];
    int t = threadIdx.x;
    int w = t >> 6, lane = t & 63;
    int slot = lane / 10;
    int m = lane - slot * 10;

    for (int n0 = blockIdx.x * 4; n0 < NN; n0 += gridDim.x * 4) {
        int n = n0 + w;
        int e0 = offs[n], c = cnt[n];

        float acc[4] = {0.f, 0.f, 0.f, 0.f};
        for (int base = 0; base < c; base += 64) {
            int bc = min(c - base, 64);
            int li = (lane < bc) ? lane : (bc - 1);
            unsigned pl = pay[e0 + base + li];
            for (int g = 0; g < bc; g += 6) {
                int je = g + slot;
                int js = je & 63;
                unsigned v = (unsigned)__shfl((int)pl, js);
                int   sj = pdec_s(v);
                float pj = pdec_p(v);
                bool valid = (slot < 6) && (je < bc);
                uint4 gv = *((const uint4*)(hw2b + (size_t)sj * 40) + m);
                float v0 = fmaf(pj, bfhi(gv.x) - bflo(gv.x), bflo(gv.x));
                float v1 = fmaf(pj, bfhi(gv.y) - bflo(gv.y), bflo(gv.y));
                float v2 = fmaf(pj, bfhi(gv.z) - bflo(gv.z), bflo(gv.z));
                float v3 = fmaf(pj, bfhi(gv.w) - bflo(gv.w), bflo(gv.w));
                acc[0] += valid ? v0 : 0.0f;
                acc[1] += valid ? v1 : 0.0f;
                acc[2] += valid ? v2 : 0.0f;
                acc[3] += valid ? v3 : 0.0f;
            }
        }
#pragma unroll
        for (int j = 0; j < 4; j++) acc[j] += __shfl(acc[j], (lane + 30) & 63);
#pragma unroll
        for (int j = 0; j < 4; j++)
            acc[j] += __shfl(acc[j], (lane + 10) & 63) + __shfl(acc[j], (lane + 20) & 63);

        asm volatile("" ::: "memory");
        if (lane < 10) {
            scr[w][4 * m]     = acc[0];
            scr[w][4 * m + 1] = acc[1];
            scr[w][4 * m + 2] = acc[2];
            scr[w][4 * m + 3] = acc[3];
        }
        asm volatile("" ::: "memory");

        float inv = 1.0f / fmaxf((float)c, 1.0f);
        float r = 0.0f;
        if (lane < OUTC)
            r = fmaf(scr[w][lane], inv, rt[(size_t)n * OUTC + lane]);

        float mx = (lane < OUTC) ? r : -1e30f;
#pragma unroll
        for (int off = 32; off > 0; off >>= 1) mx = fmaxf(mx, __shfl_xor(mx, off));
        float ex = (lane < OUTC) ? expf(r - mx) : 0.0f;
#pragma unroll
        for (int off = 32; off > 0; off >>= 1) ex += __shfl_xor(ex, off);
        float lse = mx + logf(ex);

        if (lane < OUTC) out[(size_t)n * OUTC + lane] = r - lse;
    }
}

// ---------------------------------------------------------------------------
extern "C" void kernel_launch(void* const* d_in, const int* in_sizes, int n_in,
                              void* d_out, int out_size, void* d_ws, size_t ws_size,
                              hipStream_t stream)
{
    const float* x     = (const float*)d_in[0];
    const int*   ei    = (const int*)  d_in[1];
    const float* ea    = (const float*)d_in[2];
    const float* W1    = (const float*)d_in[3];
    const float* root1 = (const float*)d_in[4];
    const float* b1    = (const float*)d_in[5];
    const float* W2    = (const float*)d_in[6];
    const float* root2 = (const float*)d_in[7];
    const float* b2    = (const float*)d_in[8];
    float* out = (float*)d_out;

    const int* src = ei;
    const int* dst = ei + NE;

    // workspace layout (~65 MB, all 16B-aligned chunks)
    char* wsp = (char*)d_ws;
    int*  cnt    = (int*)wsp;  wsp += sizeof(int) * NN;
    int*  offs   = (int*)wsp;  wsp += sizeof(int) * NN;
    int*  cursor = (int*)wsp;  wsp += sizeof(int) * NN;
    int*  bsum   = (int*)wsp;  wsp += sizeof(int) * 256;
    unsigned* pay = (unsigned*)wsp; wsp += sizeof(unsigned) * NE;                 // 6.4 MB
    unsigned* xb = (unsigned*)wsp; wsp += sizeof(unsigned) * (size_t)NN * (INC/2);// 6.4 MB
    ushort* Apre = (ushort*)wsp; wsp += sizeof(ushort) * (size_t)NN * 96;         // 19.2 MB
    ushort* hw2b = (ushort*)wsp; wsp += sizeof(ushort) * (size_t)NN * 80;         // 16 MB
    float* rt    = (float*)wsp; wsp += sizeof(float) * (size_t)NN * OUTC;         // 16 MB
    ushort* W1T  = (ushort*)wsp; wsp += sizeof(ushort) * 64 * 96;
    ushort* W2T  = (ushort*)wsp; wsp += sizeof(ushort) * 128 * 64;

    hipMemsetAsync(cnt, 0, sizeof(int) * NN, stream);

    int nb = (NN + 511) / 512;
    k_xb      <<<(NN * INC / 2 + 255) / 256, 256, 0, stream>>>(x, xb);
    k_wprep   <<<(64 * 96 + 128 * 64 + 255) / 256, 256, 0, stream>>>(W1, root1, W2, root2, W1T, W2T);
    k_hist    <<<NE / 256, 256, 0, stream>>>(dst, cnt);
    k_scan1   <<<nb, 512, 0, stream>>>(cnt, bsum);
    k_scan2   <<<1, 64, 0, stream>>>(bsum, nb);
    k_scan3   <<<nb, 512, 0, stream>>>(cnt, bsum, offs, cursor);
    k_scatter8<<<(NE / 2560) * 8, 256, 0, stream>>>(src, dst, ea, cursor, pay);

    k_agg1    <<<2048, 256, 0, stream>>>(xb, pay, offs, cnt, Apre);
    k_node_mfma<<<(NN + 63) / 64, 256, 0, stream>>>(Apre, W1T, W2T, b1, b2, hw2b, rt);
    k_agg2f   <<<2048, 256, 0, stream>>>((const unsigned*)hw2b, rt, pay, offs, cnt, out);
}

// Round 8
// 178.590 us; speedup vs baseline: 5.2774x; 1.6563x over previous
//
#include <hip/hip_runtime.h>
#include <math.h>

#define NN   100000
#define NE   1600000
#define INC  32
#define HID  64
#define OUTC 40
#define NBUCK 391          // ceil(NN/256) coarse dst-buckets (256 nodes each)
#define BCAP  5120         // slab capacity per bucket (mean 4096, +16 sigma)

typedef short bf16x8 __attribute__((ext_vector_type(8)));
typedef float f32x4  __attribute__((ext_vector_type(4)));

// bf16 helpers (round-to-nearest-even)
__device__ inline unsigned f2bf(float f) {
    unsigned u = __float_as_uint(f);
    return (u + 0x7fffu + ((u >> 16) & 1u)) >> 16;
}
__device__ inline unsigned packbf(float a, float b) {
    return f2bf(a) | (f2bf(b) << 16);
}
__device__ inline float bflo(unsigned u) { return __uint_as_float(u << 16); }
__device__ inline float bfhi(unsigned u) { return __uint_as_float(u & 0xffff0000u); }

// payload decode: src in bits 0-16, p (15-bit fixed) in bits 17-31
__device__ inline int   pdec_s(unsigned v) { return (int)(v & 0x1FFFFu); }
__device__ inline float pdec_p(unsigned v) { return (float)(v >> 17) * (1.0f / 32767.0f); }

// ---------------------------------------------------------------------------
// Binning pass: block-local histogram + one global atomicAdd per bucket per
// block, then run-writes of 8B payloads into per-bucket slabs.
// ---------------------------------------------------------------------------
__global__ __launch_bounds__(256) void k_bin(
    const int* __restrict__ src, const int* __restrict__ dst,
    const float* __restrict__ pseudo,
    int* __restrict__ gcur, uint2* __restrict__ slab)
{
    __shared__ int lh[NBUCK];
    __shared__ int lb[NBUCK];
    int t = threadIdx.x;
    for (int i = t; i < NBUCK; i += 256) lh[i] = 0;
    __syncthreads();

    int base = blockIdx.x * 4096;
#pragma unroll
    for (int i = 0; i < 16; i++) {
        int e = base + i * 256 + t;
        if (e < NE) atomicAdd(&lh[dst[e] >> 8], 1);
    }
    __syncthreads();
    for (int i = t; i < NBUCK; i += 256) {
        int c = lh[i];
        lb[i] = c ? atomicAdd(&gcur[i], c) : 0;
        lh[i] = 0;
    }
    __syncthreads();
#pragma unroll
    for (int i = 0; i < 16; i++) {
        int e = base + i * 256 + t;
        if (e < NE) {
            int d = dst[e];
            int b = d >> 8;
            int loc = atomicAdd(&lh[b], 1);
            unsigned pq = (unsigned)__float2int_rn(pseudo[e] * 32767.0f);
            slab[(size_t)b * BCAP + lb[b] + loc] =
                make_uint2((unsigned)src[e] | (pq << 17), (unsigned)(d & 255));
        }
    }
}

// exclusive scan of bucket sizes (one block)
__global__ __launch_bounds__(512) void k_bscan(const int* __restrict__ gcur,
                                               int* __restrict__ bbase)
{
    __shared__ int tmp[512];
    int t = threadIdx.x;
    int v = (t < NBUCK) ? gcur[t] : 0;
    tmp[t] = v;
    __syncthreads();
    for (int off = 1; off < 512; off <<= 1) {
        int add = (t >= off) ? tmp[t - off] : 0;
        __syncthreads();
        tmp[t] += add;
        __syncthreads();
    }
    if (t < NBUCK) bbase[t] = tmp[t] - v;
}

// Per-bucket CSR finalize: counts, offsets, and dst-ordered 4B payloads.
// Bucket's pay window (~16-20 KB) is written in one hot burst.
__global__ __launch_bounds__(256) void k_csr(
    const uint2* __restrict__ slab, const int* __restrict__ gcur,
    const int* __restrict__ bbase,
    int* __restrict__ cnt, int* __restrict__ offs, unsigned* __restrict__ pay)
{
    __shared__ int cl[256], ol[256], cur[256];
    __shared__ int ssz, sbase;
    int b = blockIdx.x, t = threadIdx.x;
    if (t == 0) { ssz = gcur[b]; sbase = bbase[b]; }
    cl[t] = 0;
    __syncthreads();
    int sz = ssz, base0 = sbase;
    const uint2* sl = slab + (size_t)b * BCAP;

    for (int i = t; i < sz; i += 256) atomicAdd(&cl[sl[i].y], 1);
    __syncthreads();

    int v = cl[t];
    ol[t] = v;
    __syncthreads();
    for (int off = 1; off < 256; off <<= 1) {
        int add = (t >= off) ? ol[t - off] : 0;
        __syncthreads();
        ol[t] += add;
        __syncthreads();
    }
    int excl = ol[t] - v;
    __syncthreads();
    ol[t] = excl;
    cur[t] = 0;
    int node = b * 256 + t;
    if (node < NN) { cnt[node] = v; offs[node] = base0 + excl; }
    __syncthreads();

    for (int i = t; i < sz; i += 256) {
        uint2 v2 = sl[i];
        int loc = atomicAdd(&cur[v2.y], 1);
        pay[base0 + ol[v2.y] + loc] = v2.x;
    }
}

// ---------------------------------------------------------------------------
// x -> bf16 packed rows
// ---------------------------------------------------------------------------
__global__ __launch_bounds__(256) void k_xb(const float* __restrict__ x,
                                            unsigned* __restrict__ xb)
{
    int i = blockIdx.x * 256 + threadIdx.x;
    if (i >= NN * INC / 2) return;
    float2 v = ((const float2*)x)[i];
    xb[i] = packbf(v.x, v.y);
}

// ---------------------------------------------------------------------------
// Weight prep: W1T[64][96] = [W1_0; W1_1; root1]^T (bf16, o-major)
//              W2T[128][64]: row j<80: j=2o+khat -> W2[khat][:,o]; 80..119:
//              root2[:, j-80]; 120..127: 0.  (bf16, col(j)-major)
// ---------------------------------------------------------------------------
__global__ __launch_bounds__(256) void k_wprep(
    const float* __restrict__ W1, const float* __restrict__ root1,
    const float* __restrict__ W2, const float* __restrict__ root2,
    ushort* __restrict__ W1T, ushort* __restrict__ W2T)
{
    int i = blockIdx.x * 256 + threadIdx.x;
    if (i < 64 * 96) {
        int o = i / 96, k = i % 96;
        float v;
        if (k < 32)      v = W1[k * HID + o];
        else if (k < 64) v = W1[INC * HID + (k - 32) * HID + o];
        else             v = root1[(k - 64) * HID + o];
        W1T[i] = (ushort)f2bf(v);
    }
    int i2 = i - 64 * 96;
    if (i2 >= 0 && i2 < 128 * 64) {
        int j = i2 / 64, k = i2 % 64;
        float v = 0.0f;
        if (j < 80)       v = W2[(j & 1) * (HID * OUTC) + k * OUTC + (j >> 1)];
        else if (j < 120) v = root2[k * OUTC + (j - 80)];
        W2T[i2] = (ushort)f2bf(v);
    }
}

// ---------------------------------------------------------------------------
// Layer 1 gather: wave per node, 8 edges per vmem instruction.
// Emits Apre[n][96] bf16 = [sum((1-p)x)*inv | sum(p*x)*inv | x]
// ---------------------------------------------------------------------------
__global__ __launch_bounds__(256) void k_agg1(
    const unsigned* __restrict__ xb, const unsigned* __restrict__ pay,
    const int* __restrict__ offs, const int* __restrict__ cnt,
    ushort* __restrict__ Apre)
{
    int t = threadIdx.x;
    int w = t >> 6, lane = t & 63;
    int slot = lane >> 3, sub = lane & 7;

    for (int n0 = blockIdx.x * 4; n0 < NN; n0 += gridDim.x * 4) {
        int n = n0 + w;
        int e0 = offs[n], c = cnt[n];

        float a0[4] = {0.f, 0.f, 0.f, 0.f};
        float a1[4] = {0.f, 0.f, 0.f, 0.f};

        for (int base = 0; base < c; base += 64) {
            int bc = min(c - base, 64);
            int li = (lane < bc) ? lane : (bc - 1);
            unsigned pl = pay[e0 + base + li];
            for (int g = 0; g < bc; g += 8) {
                int je = g + slot;
                unsigned v = (unsigned)__shfl((int)pl, je);
                int   sj = pdec_s(v);
                float pj = pdec_p(v);
                bool valid = je < bc;
                float w1v = valid ? pj : 0.0f;
                float w0v = valid ? (1.0f - pj) : 0.0f;
                uint2 gv = *((const uint2*)(xb + (size_t)sj * (INC / 2)) + sub);
                float f0 = bflo(gv.x), f1 = bfhi(gv.x);
                float f2 = bflo(gv.y), f3 = bfhi(gv.y);
                a0[0] = fmaf(w0v, f0, a0[0]); a0[1] = fmaf(w0v, f1, a0[1]);
                a0[2] = fmaf(w0v, f2, a0[2]); a0[3] = fmaf(w0v, f3, a0[3]);
                a1[0] = fmaf(w1v, f0, a1[0]); a1[1] = fmaf(w1v, f1, a1[1]);
                a1[2] = fmaf(w1v, f2, a1[2]); a1[3] = fmaf(w1v, f3, a1[3]);
            }
        }
#pragma unroll
        for (int mask = 8; mask <= 32; mask <<= 1) {
#pragma unroll
            for (int j = 0; j < 4; j++) {
                a0[j] += __shfl_xor(a0[j], mask);
                a1[j] += __shfl_xor(a1[j], mask);
            }
        }
        if (slot == 0) {
            float inv = 1.0f / fmaxf((float)c, 1.0f);
            ushort* ap = Apre + (size_t)n * 96;
            *(uint2*)(ap + sub * 4) =
                make_uint2(packbf(a0[0] * inv, a0[1] * inv),
                           packbf(a0[2] * inv, a0[3] * inv));
            *(uint2*)(ap + 32 + sub * 4) =
                make_uint2(packbf(a1[0] * inv, a1[1] * inv),
                           packbf(a1[2] * inv, a1[3] * inv));
            uint2 xv = *((const uint2*)(xb + (size_t)n * 16) + sub);
            *(uint2*)(ap + 64 + sub * 4) = xv;
        }
    }
}

// ---------------------------------------------------------------------------
// Node transform on MFMA: 64 nodes/block, 4 waves x 16-node M-tiles.
// ---------------------------------------------------------------------------
__global__ __launch_bounds__(256) void k_node_mfma(
    const ushort* __restrict__ Apre, const ushort* __restrict__ W1T,
    const ushort* __restrict__ W2T, const float* __restrict__ b1,
    const float* __restrict__ b2,
    ushort* __restrict__ hw2b_us, float* __restrict__ rt)
{
    __shared__ ushort sA[64 * 104];
    __shared__ ushort sW1[64 * 104];
    __shared__ ushort sW2[128 * 72];
    __shared__ ushort sH[4 * 16 * 72];
    __shared__ float sb1[HID], sb2[OUTC];

    int t = threadIdx.x;
    int nbase = blockIdx.x * 64;

#pragma unroll
    for (int i = 0; i < 3; i++) {
        int idx = t + i * 256;
        int row = idx / 12, c = idx % 12;
        uint4 v = make_uint4(0, 0, 0, 0);
        if (nbase + row < NN)
            v = *(const uint4*)(Apre + (size_t)(nbase + row) * 96 + c * 8);
        *(uint4*)(sA + row * 104 + c * 8) = v;
    }
#pragma unroll
    for (int i = 0; i < 3; i++) {
        int idx = t + i * 256;
        int row = idx / 12, c = idx % 12;
        *(uint4*)(sW1 + row * 104 + c * 8) =
            *(const uint4*)(W1T + row * 96 + c * 8);
    }
#pragma unroll
    for (int i = 0; i < 4; i++) {
        int idx = t + i * 256;
        int row = idx / 8, c = idx % 8;
        *(uint4*)(sW2 + row * 72 + c * 8) =
            *(const uint4*)(W2T + row * 64 + c * 8);
    }
    if (t < HID) sb1[t] = b1[t];
    if (t >= 64 && t < 64 + OUTC) sb2[t - 64] = b2[t - 64];
    __syncthreads();

    int w = t >> 6, lane = t & 63;
    int lm = lane & 15, lk = lane >> 4;

    f32x4 acc[4];
#pragma unroll
    for (int nt = 0; nt < 4; nt++) acc[nt] = (f32x4){0.f, 0.f, 0.f, 0.f};
#pragma unroll
    for (int kk = 0; kk < 3; kk++) {
        bf16x8 af = *(const bf16x8*)(sA + (w * 16 + lm) * 104 + kk * 32 + lk * 8);
#pragma unroll
        for (int nt = 0; nt < 4; nt++) {
            bf16x8 bfr = *(const bf16x8*)(sW1 + (nt * 16 + lm) * 104 + kk * 32 + lk * 8);
            acc[nt] = __builtin_amdgcn_mfma_f32_16x16x32_bf16(af, bfr, acc[nt], 0, 0, 0);
        }
    }

    ushort* hrow = sH + w * 16 * 72;
#pragma unroll
    for (int nt = 0; nt < 4; nt++) {
#pragma unroll
        for (int r = 0; r < 4; r++) {
            float v = acc[nt][r] + sb1[nt * 16 + lm];
            v = (v > 0.0f) ? v : (expf(v) - 1.0f);
            hrow[(lk * 4 + r) * 72 + nt * 16 + lm] = (ushort)f2bf(v);
        }
    }
    asm volatile("" ::: "memory");

    f32x4 g[8];
#pragma unroll
    for (int nt = 0; nt < 8; nt++) g[nt] = (f32x4){0.f, 0.f, 0.f, 0.f};
#pragma unroll
    for (int kk = 0; kk < 2; kk++) {
        bf16x8 af = *(const bf16x8*)(hrow + lm * 72 + kk * 32 + lk * 8);
#pragma unroll
        for (int nt = 0; nt < 8; nt++) {
            bf16x8 bfr = *(const bf16x8*)(sW2 + (nt * 16 + lm) * 72 + kk * 32 + lk * 8);
            g[nt] = __builtin_amdgcn_mfma_f32_16x16x32_bf16(af, bfr, g[nt], 0, 0, 0);
        }
    }

#pragma unroll
    for (int nt = 0; nt < 8; nt++) {
        int j = nt * 16 + lm;
#pragma unroll
        for (int r = 0; r < 4; r++) {
            int node = nbase + w * 16 + lk * 4 + r;
            if (node >= NN) continue;
            float v = g[nt][r];
            if (j < 80)
                hw2b_us[(size_t)node * 80 + j] = (ushort)f2bf(v);
            else if (j < 120)
                rt[(size_t)node * 40 + (j - 80)] = v + sb2[j - 80];
        }
    }
}

// ---------------------------------------------------------------------------
// Layer 2: wave per node, 6 edges per vmem instruction (10 lanes x uint4).
// ---------------------------------------------------------------------------
__global__ __launch_bounds__(256) void k_agg2f(
    const unsigned* __restrict__ hw2b, const float* __restrict__ rt,
    const unsigned* __restrict__ pay, const int* __restrict__ offs,
    const int* __restrict__ cnt, float* __restrict__ out)
{
    __shared__ float scr[4][OUTC];
    int t = threadIdx.x;
    int w = t >> 6, lane = t & 63;
    int slot = lane / 10;
    int m = lane - slot * 10;

    for (int n0 = blockIdx.x * 4; n0 < NN; n0 += gridDim.x * 4) {
        int n = n0 + w;
        int e0 = offs[n], c = cnt[n];

        float acc[4] = {0.f, 0.f, 0.f, 0.f};
        for (int base = 0; base < c; base += 64) {
            int bc = min(c - base, 64);
            int li = (lane < bc) ? lane : (bc - 1);
            unsigned pl = pay[e0 + base + li];
            for (int g = 0; g < bc; g += 6) {
                int je = g + slot;
                int js = je & 63;
                unsigned v = (unsigned)__shfl((int)pl, js);
                int   sj = pdec_s(v);
                float pj = pdec_p(v);
                bool valid = (slot < 6) && (je < bc);
                uint4 gv = *((const uint4*)(hw2b + (size_t)sj * 40) + m);
                float v0 = fmaf(pj, bfhi(gv.x) - bflo(gv.x), bflo(gv.x));
                float v1 = fmaf(pj, bfhi(gv.y) - bflo(gv.y), bflo(gv.y));
                float v2 = fmaf(pj, bfhi(gv.z) - bflo(gv.z), bflo(gv.z));
                float v3 = fmaf(pj, bfhi(gv.w) - bflo(gv.w), bflo(gv.w));
                acc[0] += valid ? v0 : 0.0f;
                acc[1] += valid ? v1 : 0.0f;
                acc[2] += valid ? v2 : 0.0f;
                acc[3] += valid ? v3 : 0.0f;
            }
        }
#pragma unroll
        for (int j = 0; j < 4; j++) acc[j] += __shfl(acc[j], (lane + 30) & 63);
#pragma unroll
        for (int j = 0; j < 4; j++)
            acc[j] += __shfl(acc[j], (lane + 10) & 63) + __shfl(acc[j], (lane + 20) & 63);

        asm volatile("" ::: "memory");
        if (lane < 10) {
            scr[w][4 * m]     = acc[0];
            scr[w][4 * m + 1] = acc[1];
            scr[w][4 * m + 2] = acc[2];
            scr[w][4 * m + 3] = acc[3];
        }
        asm volatile("" ::: "memory");

        float inv = 1.0f / fmaxf((float)c, 1.0f);
        float r = 0.0f;
        if (lane < OUTC)
            r = fmaf(scr[w][lane], inv, rt[(size_t)n * OUTC + lane]);

        float mx = (lane < OUTC) ? r : -1e30f;
#pragma unroll
        for (int off = 32; off > 0; off >>= 1) mx = fmaxf(mx, __shfl_xor(mx, off));
        float ex = (lane < OUTC) ? expf(r - mx) : 0.0f;
#pragma unroll
        for (int off = 32; off > 0; off >>= 1) ex += __shfl_xor(ex, off);
        float lse = mx + logf(ex);

        if (lane < OUTC) out[(size_t)n * OUTC + lane] = r - lse;
    }
}

// ---------------------------------------------------------------------------
extern "C" void kernel_launch(void* const* d_in, const int* in_sizes, int n_in,
                              void* d_out, int out_size, void* d_ws, size_t ws_size,
                              hipStream_t stream)
{
    const float* x     = (const float*)d_in[0];
    const int*   ei    = (const int*)  d_in[1];
    const float* ea    = (const float*)d_in[2];
    const float* W1    = (const float*)d_in[3];
    const float* root1 = (const float*)d_in[4];
    const float* b1    = (const float*)d_in[5];
    const float* W2    = (const float*)d_in[6];
    const float* root2 = (const float*)d_in[7];
    const float* b2    = (const float*)d_in[8];
    float* out = (float*)d_out;

    const int* src = ei;
    const int* dst = ei + NE;

    // workspace layout (~81.6 MB)
    char* wsp = (char*)d_ws;
    int*  cnt   = (int*)wsp;  wsp += sizeof(int) * NN;                              // 400 KB
    int*  offs  = (int*)wsp;  wsp += sizeof(int) * NN;                              // 400 KB
    int*  gcur  = (int*)wsp;  wsp += sizeof(int) * 512;
    int*  bbase = (int*)wsp;  wsp += sizeof(int) * 512;
    unsigned* pay = (unsigned*)wsp; wsp += sizeof(unsigned) * NE;                   // 6.4 MB
    unsigned* xb  = (unsigned*)wsp; wsp += sizeof(unsigned) * (size_t)NN * (INC/2); // 6.4 MB
    ushort* Apre  = (ushort*)wsp; wsp += sizeof(ushort) * (size_t)NN * 96;          // 19.2 MB
    ushort* hw2b  = (ushort*)wsp; wsp += sizeof(ushort) * (size_t)NN * 80;          // 16 MB
    float* rt     = (float*)wsp; wsp += sizeof(float) * (size_t)NN * OUTC;          // 16 MB
    ushort* W1T   = (ushort*)wsp; wsp += sizeof(ushort) * 64 * 96;
    ushort* W2T   = (ushort*)wsp; wsp += sizeof(ushort) * 128 * 64;
    wsp = (char*)(((size_t)wsp + 15) & ~(size_t)15);
    uint2* slab   = (uint2*)wsp; wsp += sizeof(uint2) * (size_t)NBUCK * BCAP;       // 16 MB

    hipMemsetAsync(gcur, 0, sizeof(int) * 512, stream);

    k_xb    <<<(NN * INC / 2 + 255) / 256, 256, 0, stream>>>(x, xb);
    k_wprep <<<(64 * 96 + 128 * 64 + 255) / 256, 256, 0, stream>>>(W1, root1, W2, root2, W1T, W2T);
    k_bin   <<<(NE + 4095) / 4096, 256, 0, stream>>>(src, dst, ea, gcur, slab);
    k_bscan <<<1, 512, 0, stream>>>(gcur, bbase);
    k_csr   <<<NBUCK, 256, 0, stream>>>(slab, gcur, bbase, cnt, offs, pay);

    k_agg1  <<<2048, 256, 0, stream>>>(xb, pay, offs, cnt, Apre);
    k_node_mfma<<<(NN + 63) / 64, 256, 0, stream>>>(Apre, W1T, W2T, b1, b2, hw2b, rt);
    k_agg2f <<<2048, 256, 0, stream>>>((const unsigned*)hw2b, rt, pay, offs, cnt, out);
}